// Round 3
// baseline (1096.761 us; speedup 1.0000x reference)
//
#include <hip/hip_runtime.h>
#include <hip/hip_bf16.h>

typedef __bf16 bf16_t;
typedef bf16_t bf16x8 __attribute__((ext_vector_type(8)));
typedef float f32x4 __attribute__((ext_vector_type(4)));

// ---------------------------------------------------------------- helpers
__device__ __forceinline__ void gl_lds16(const bf16_t* g, bf16_t* l) {
  __builtin_amdgcn_global_load_lds(
      (const __attribute__((address_space(1))) void*)g,
      (__attribute__((address_space(3))) void*)l,
      16, 0, 0);
}

__device__ __forceinline__ void load8f(const bf16_t* p, float* f) {
  bf16x8 v = *(const bf16x8*)p;
#pragma unroll
  for (int e = 0; e < 8; ++e) f[e] = (float)v[e];
}
__device__ __forceinline__ void store8f(bf16_t* p, const float* f) {
  bf16x8 v;
#pragma unroll
  for (int e = 0; e < 8; ++e) v[e] = (bf16_t)f[e];
  *(bf16x8*)p = v;
}

// ---------------------------------------------------------------- fp32 -> bf16 (x)
__global__ __launch_bounds__(256) void cvt_f32_to_bf16(const float* __restrict__ in,
                                                       bf16_t* __restrict__ o) {
  size_t gid = (size_t)blockIdx.x * 256 + threadIdx.x;
  const float4* p = (const float4*)in + gid * 2;
  float4 a = p[0], b = p[1];
  bf16x8 v;
  v[0] = (bf16_t)a.x; v[1] = (bf16_t)a.y; v[2] = (bf16_t)a.z; v[3] = (bf16_t)a.w;
  v[4] = (bf16_t)b.x; v[5] = (bf16_t)b.y; v[6] = (bf16_t)b.z; v[7] = (bf16_t)b.w;
  *(bf16x8*)(o + gid * 8) = v;
}

// ---------------------------------------------------------------- weight transpose + cast: w[K][N] -> wT[N][K] bf16
__global__ __launch_bounds__(256) void transpose_to_bf16(const float* __restrict__ w,
                                                         bf16_t* __restrict__ wT,
                                                         int K, int N) {
  __shared__ float t[32][33];
  int bx = blockIdx.x, by = blockIdx.y;
  int tx = threadIdx.x & 31, ty = threadIdx.x >> 5;
#pragma unroll
  for (int r = ty; r < 32; r += 8)
    t[r][tx] = w[(size_t)(by * 32 + r) * N + bx * 32 + tx];
  __syncthreads();
#pragma unroll
  for (int r = ty; r < 32; r += 8)
    wT[(size_t)(bx * 32 + r) * K + by * 32 + tx] = (bf16_t)t[tx][r];
}

// ---------------------------------------------------------------- 256x256 8-phase GEMM (T1+T3+T4+T5)
// C[M][N] = A[M][K] @ Bt[N][K]^T.  8 waves (512 thr), BK=64, dbuf LDS 128 KiB,
// 4 phases/K-tile, counted vmcnt(6) at tile boundary only. Linear LDS (no T2 yet).
// EPI 0: bf16 C.  EPI 1: fp32 C + bias.
template <int EPI>
__global__ __launch_bounds__(512, 2) void gemm256(const bf16_t* __restrict__ A,
                                                  const bf16_t* __restrict__ Bt,
                                                  void* __restrict__ Cp,
                                                  const float* __restrict__ bias,
                                                  int M, int N, int K, int ldc, int nTilesN) {
  __shared__ __align__(16) bf16_t As[2 * 256 * 64];   // [buf][256 rows][64 k]
  __shared__ __align__(16) bf16_t Bs[2 * 256 * 64];
  const int tid = threadIdx.x;
  const int w = tid >> 6, lane = tid & 63;

  // T1: bijective XCD swizzle (gridDim.x % 8 == 0), then ntile-fast decode so
  // consecutive wgids on one XCD share the A-panel (0.5 MiB, L2-resident).
  int nwg = gridDim.x;
  int chunk = nwg >> 3;
  int wgid = (blockIdx.x & 7) * chunk + (blockIdx.x >> 3);
  int mt = wgid / nTilesN, ntile = wgid % nTilesN;
  const int bm = mt * 256, bn = ntile * 256;

  const int wr = w >> 2, wc = w & 3;          // 2x4 wave grid; wave tile 128x64
  const int lr = lane & 15, lg = lane >> 4;
  const int nt = K >> 6;

  f32x4 acc[8][4] = {};

  // stage one half-tile (128 rows x 64 k = 16 KB): 2 gload_lds per wave
  auto stageHalf = [&](const bf16_t* __restrict__ G, int rbase, int kt, int ld,
                       bf16_t* lbuf, int h) {
#pragma unroll
    for (int j = 0; j < 2; ++j) {
      int b = j * 8 + w;                                   // 16 chunk-blocks of 1 KB
      gl_lds16(G + (size_t)(rbase + h * 128 + b * 8 + (lane >> 3)) * ld + kt + (lane & 7) * 8,
               lbuf + h * 8192 + b * 512);                 // wave-uniform LDS base
    }
  };

  // prologue: tiles 0 and 1 fully staged
  stageHalf(Bt, bn, 0, K, Bs, 0); stageHalf(Bt, bn, 0, K, Bs, 1);
  stageHalf(A, bm, 0, K, As, 0);  stageHalf(A, bm, 0, K, As, 1);
  if (nt > 1) {
    stageHalf(Bt, bn, 64, K, Bs + 16384, 0); stageHalf(Bt, bn, 64, K, Bs + 16384, 1);
    stageHalf(A, bm, 64, K, As + 16384, 0);  stageHalf(A, bm, 64, K, As + 16384, 1);
    asm volatile("s_waitcnt vmcnt(8)" ::: "memory");       // tile 0 landed
  } else {
    asm volatile("s_waitcnt vmcnt(0)" ::: "memory");
  }
  __syncthreads();

  for (int t = 0; t < nt; ++t) {
    const int c = t & 1;
    bf16_t* Abuf = As + c * 16384;
    bf16_t* Bbuf = Bs + c * 16384;
    const bool pf = (t + 2) < nt;
    const int kt2 = (t + 2) << 6;
    bf16x8 bfrag[4][2];

#pragma unroll
    for (int p = 0; p < 4; ++p) {
      // ---- ds-loads for this phase (A rows 32p..32p+31 of the wave's half)
      bf16x8 afrag[2][2];
#pragma unroll
      for (int fi = 0; fi < 2; ++fi)
#pragma unroll
        for (int kk = 0; kk < 2; ++kk)
          afrag[fi][kk] = *(const bf16x8*)&Abuf[(wr * 128 + p * 32 + fi * 16 + lr) * 64 + kk * 32 + lg * 8];
      if (p == 0) {
#pragma unroll
        for (int fj = 0; fj < 4; ++fj)
#pragma unroll
          for (int kk = 0; kk < 2; ++kk)
            bfrag[fj][kk] = *(const bf16x8*)&Bbuf[(wc * 64 + fj * 16 + lr) * 64 + kk * 32 + lg * 8];
      }
      // ---- stage tile t+2 into the buffer being drained (read-liveness safe order)
      if (pf) {
        if (p == 1) stageHalf(Bt, bn, kt2, K, Bbuf, 0);
        if (p == 2) stageHalf(Bt, bn, kt2, K, Bbuf, 1);
        if (p == 3) { stageHalf(A, bm, kt2, K, Abuf, 0); stageHalf(A, bm, kt2, K, Abuf, 1); }
      }
      __builtin_amdgcn_s_barrier();
      asm volatile("s_waitcnt lgkmcnt(0)" ::: "memory");
      __builtin_amdgcn_sched_barrier(0);
      __builtin_amdgcn_s_setprio(1);
#pragma unroll
      for (int kk = 0; kk < 2; ++kk)
#pragma unroll
        for (int fi = 0; fi < 2; ++fi)
#pragma unroll
          for (int fj = 0; fj < 4; ++fj)
            acc[p * 2 + fi][fj] = __builtin_amdgcn_mfma_f32_16x16x32_bf16(
                afrag[fi][kk], bfrag[fj][kk], acc[p * 2 + fi][fj], 0, 0, 0);
      __builtin_amdgcn_s_setprio(0);
      if (p == 3) {
        if (pf) asm volatile("s_waitcnt vmcnt(6)" ::: "memory");   // counted: tile t+1 landed
        else    asm volatile("s_waitcnt vmcnt(0)" ::: "memory");   // tail drain
      }
      __builtin_amdgcn_s_barrier();
    }
  }

#pragma unroll
  for (int fi = 0; fi < 8; ++fi)
#pragma unroll
    for (int fj = 0; fj < 4; ++fj)
#pragma unroll
      for (int r = 0; r < 4; ++r) {
        int row = bm + wr * 128 + fi * 16 + lg * 4 + r;
        int col = bn + wc * 64 + fj * 16 + lr;
        float v = acc[fi][fj][r];
        if (EPI == 0) ((bf16_t*)Cp)[(size_t)row * ldc + col] = (bf16_t)v;
        else          ((float*)Cp)[(size_t)row * ldc + col] = v + bias[col];
      }
}

// ---------------------------------------------------------------- pyramid coarsen level 1 (from C1)
__global__ __launch_bounds__(256) void coarsen1(const bf16_t* __restrict__ C1,
                                                bf16_t* __restrict__ Pq,
                                                bf16_t* __restrict__ Pk,
                                                bf16_t* __restrict__ Pv) {
  int gid = blockIdx.x * 256 + threadIdx.x;      // 64 hg * 4096 rows * 8 d8
  int d8 = gid & 7;
  int r = (gid >> 3) & 4095;
  int hg = gid >> 15;
  size_t base0 = ((size_t)(hg >> 4) * 8192 + 2 * r) * 3072 + (hg & 15) * 64 + d8 * 8;
  size_t base1 = base0 + 3072;
  float q0[8], q1[8], k0[8], k1[8], v0[8], v1[8], t[8];
  load8f(C1 + base0, q0);        load8f(C1 + base1, q1);
  load8f(C1 + base0 + 1024, k0); load8f(C1 + base1 + 1024, k1);
  load8f(C1 + base0 + 2048, v0); load8f(C1 + base1 + 2048, v1);
  size_t o = ((size_t)hg * 8160 + r) * 64 + d8 * 8;
#pragma unroll
  for (int e = 0; e < 8; ++e) t[e] = 0.5f * (q0[e] + q1[e]);
  store8f(Pq + o, t);
#pragma unroll
  for (int e = 0; e < 8; ++e) t[e] = 0.5f * (k0[e] + k1[e]);
  store8f(Pk + o, t);
#pragma unroll
  for (int e = 0; e < 8; ++e) t[e] = v0[e] + v1[e];
  store8f(Pv + o, t);
}

// ---------------------------------------------------------------- pyramid coarsen levels 2..8, fused
// grid 512 = 64 hg x 8 d-chunks; levels sequential with __syncthreads (same-wg global rw is coherent)
__global__ __launch_bounds__(256) void coarsen_rest(bf16_t* __restrict__ Pq,
                                                    bf16_t* __restrict__ Pk,
                                                    bf16_t* __restrict__ Pv) {
  const int hg = blockIdx.x >> 3, dc = blockIdx.x & 7;
  const int tid = threadIdx.x;
  const int poffA[9] = {0, 0, 4096, 6144, 7168, 7680, 7936, 8064, 8128};
#pragma unroll 1
  for (int l = 2; l <= 8; ++l) {
    int rows = 1 << (13 - l);
    int pin = poffA[l - 1], pout = poffA[l];
    for (int r = tid; r < rows; r += 256) {
      size_t b0 = ((size_t)hg * 8160 + pin + 2 * r) * 64 + dc * 8;
      size_t b1 = b0 + 64;
      size_t o = ((size_t)hg * 8160 + pout + r) * 64 + dc * 8;
      float a0[8], a1[8], t[8];
      load8f(Pq + b0, a0); load8f(Pq + b1, a1);
#pragma unroll
      for (int e = 0; e < 8; ++e) t[e] = 0.5f * (a0[e] + a1[e]);
      store8f(Pq + o, t);
      load8f(Pk + b0, a0); load8f(Pk + b1, a1);
#pragma unroll
      for (int e = 0; e < 8; ++e) t[e] = 0.5f * (a0[e] + a1[e]);
      store8f(Pk + o, t);
      load8f(Pv + b0, a0); load8f(Pv + b1, a1);
#pragma unroll
      for (int e = 0; e < 8; ++e) t[e] = a0[e] + a1[e];
      store8f(Pv + o, t);
    }
    __syncthreads();
  }
}

// ---------------------------------------------------------------- 16x16 block attention body
__device__ __forceinline__ void attn_body(const bf16_t* qsrc_row0, size_t qstride,
                                          const bf16_t* ksrc_row0, size_t kstride,
                                          const bf16_t* vsrc_row0,
                                          float* qs, float* ks, float* vs, float* SA,
                                          int tid, float* asum_out, float* yout16x64_mode,
                                          bf16_t* yout_bf, float* yout_f32) {
  // staging done by caller
}

// per-level 16x16 block attention, finest level (reads C1, writes fp32 Y0 in d_out)
__global__ __launch_bounds__(256) void attn_l0(const bf16_t* __restrict__ C1,
                                               float* __restrict__ Y0,
                                               float* __restrict__ Asum) {
  __shared__ float qs[16 * 64], ks[16 * 65], vs[16 * 64], SA[16 * 17];
  const int tid = threadIdx.x;
  const int blk = blockIdx.x & 511;
  const int hg = blockIdx.x >> 9;

  for (int c = tid; c < 384; c += 256) {
    int tns = c >> 7;
    int idx = c & 127;
    int i = idx >> 3, d8 = idx & 7;
    int t = blk * 16 + i;
    const bf16_t* src = C1 + ((size_t)(hg >> 4) * 8192 + t) * 3072 + (hg & 15) * 64 + tns * 1024 + d8 * 8;
    bf16x8 v = *(const bf16x8*)src;
    float* dst = (tns == 0) ? &qs[i * 64 + d8 * 8]
                            : (tns == 1 ? &ks[i * 65 + d8 * 8] : &vs[i * 64 + d8 * 8]);
#pragma unroll
    for (int e = 0; e < 8; ++e) dst[e] = (float)v[e];
  }
  __syncthreads();

  const int i = tid >> 4, j = tid & 15;
  float s = 0.f;
#pragma unroll
  for (int d = 0; d < 64; ++d) s += qs[i * 64 + d] * ks[j * 65 + d];
  s *= 0.125f;
  float mx = s;
#pragma unroll
  for (int m = 8; m >= 1; m >>= 1) mx = fmaxf(mx, __shfl_xor(mx, m, 64));
  float a = expf(s - mx);
  float as = a;
#pragma unroll
  for (int m = 8; m >= 1; m >>= 1) as += __shfl_xor(as, m, 64);
  SA[i * 17 + j] = a;
  if (j == 0) Asum[(size_t)hg * 16352 + blk * 16 + i] = as;
  __syncthreads();

#pragma unroll
  for (int e = 0; e < 4; ++e) {
    int idx = tid + e * 256;
    int ii = idx >> 6, d = idx & 63;
    float y = 0.f;
#pragma unroll
    for (int jj = 0; jj < 16; ++jj) y += SA[ii * 17 + jj] * vs[jj * 64 + d];
    Y0[((size_t)hg * 8192 + blk * 16 + ii) * 64 + d] = y;
  }
}

// all coarse levels (1..8) fused in one dispatch; 32640 workgroups
__global__ __launch_bounds__(256) void attn_coarse_all(const bf16_t* __restrict__ Pq,
                                                       const bf16_t* __restrict__ Pk,
                                                       const bf16_t* __restrict__ Pv,
                                                       bf16_t* __restrict__ Yc,
                                                       float* __restrict__ Asum) {
  __shared__ float qs[16 * 64], ks[16 * 65], vs[16 * 64], SA[16 * 17];
  const int poffA[9] = {0, 0, 4096, 6144, 7168, 7680, 7936, 8064, 8128};
  const int aoffA[9] = {0, 8192, 12288, 14336, 15360, 15872, 16128, 16256, 16320};
  int bid = blockIdx.x, l = 1, cnt = 16384;
  while (bid >= cnt) { bid -= cnt; cnt >>= 1; ++l; }
  const int lg2nblk = 9 - l;
  const int blk = bid & ((1 << lg2nblk) - 1);
  const int hg = bid >> lg2nblk;
  const int kvblk = blk ^ 1;
  const int poff = poffA[l], aoff = aoffA[l];
  const int tid = threadIdx.x;

  for (int c = tid; c < 384; c += 256) {
    int tns = c >> 7;
    int idx = c & 127;
    int i = idx >> 3, d8 = idx & 7;
    int t = ((tns == 0) ? blk : kvblk) * 16 + i;
    const bf16_t* P = (tns == 0) ? Pq : (tns == 1 ? Pk : Pv);
    const bf16_t* src = P + ((size_t)hg * 8160 + poff + t) * 64 + d8 * 8;
    bf16x8 v = *(const bf16x8*)src;
    float* dst = (tns == 0) ? &qs[i * 64 + d8 * 8]
                            : (tns == 1 ? &ks[i * 65 + d8 * 8] : &vs[i * 64 + d8 * 8]);
#pragma unroll
    for (int e = 0; e < 8; ++e) dst[e] = (float)v[e];
  }
  __syncthreads();

  const int i = tid >> 4, j = tid & 15;
  float s = 0.f;
#pragma unroll
  for (int d = 0; d < 64; ++d) s += qs[i * 64 + d] * ks[j * 65 + d];
  s *= 0.125f;
  float mx = s;
#pragma unroll
  for (int m = 8; m >= 1; m >>= 1) mx = fmaxf(mx, __shfl_xor(mx, m, 64));
  float a = expf(s - mx);
  float as = a;
#pragma unroll
  for (int m = 8; m >= 1; m >>= 1) as += __shfl_xor(as, m, 64);
  SA[i * 17 + j] = a;
  if (j == 0) Asum[(size_t)hg * 16352 + aoff + blk * 16 + i] = as;
  __syncthreads();

#pragma unroll
  for (int e = 0; e < 4; ++e) {
    int idx = tid + e * 256;
    int ii = idx >> 6, d = idx & 63;
    float y = 0.f;
#pragma unroll
    for (int jj = 0; jj < 16; ++jj) y += SA[ii * 17 + jj] * vs[jj * 64 + d];
    Yc[((size_t)hg * 8160 + poff + blk * 16 + ii) * 64 + d] = (bf16_t)y;
  }
}

// ---------------------------------------------------------------- combine levels + normalize -> attn bf16 [32768][1024]
__global__ __launch_bounds__(256) void combine_kernel(const float* __restrict__ Y0,
                                                      const bf16_t* __restrict__ Yc,
                                                      const float* __restrict__ As,
                                                      bf16_t* __restrict__ attnb) {
  int gid = blockIdx.x * 256 + threadIdx.x;
  int d8 = gid & 7;
  int t = (gid >> 3) & 8191;
  int hg = gid >> 16;
  const int poffA[9] = {0, 0, 4096, 6144, 7168, 7680, 7936, 8064, 8128};
  const int aoffA[9] = {0, 8192, 12288, 14336, 15360, 15872, 16128, 16256, 16320};
  float acc[8];
  float asum = As[(size_t)hg * 16352 + t];
  {
    const float4* yp = (const float4*)(Y0 + ((size_t)hg * 8192 + t) * 64 + d8 * 8);
    float4 y0 = yp[0], y1 = yp[1];
    acc[0] = y0.x; acc[1] = y0.y; acc[2] = y0.z; acc[3] = y0.w;
    acc[4] = y1.x; acc[5] = y1.y; acc[6] = y1.z; acc[7] = y1.w;
  }
#pragma unroll
  for (int l = 1; l < 9; ++l) {
    int rc = t >> l;
    asum += As[(size_t)hg * 16352 + aoffA[l] + rc];
    bf16x8 v = *(const bf16x8*)(Yc + ((size_t)hg * 8160 + poffA[l] + rc) * 64 + d8 * 8);
#pragma unroll
    for (int e = 0; e < 8; ++e) acc[e] += (float)v[e];
  }
  float inv = 1.f / (asum + 1e-8f);
  bf16x8 v;
#pragma unroll
  for (int e = 0; e < 8; ++e) v[e] = (bf16_t)(acc[e] * inv);
  *(bf16x8*)(attnb + ((size_t)(hg >> 4) * 8192 + t) * 1024 + (hg & 15) * 64 + d8 * 8) = v;
}

// ---------------------------------------------------------------- launch
// Workspace plan (bytes), total ~453 MiB (same as passing round-2 layout):
//   C1 @0 (192M) | Pq @201326592 | Pk @268173312 | Pv @335020032 | Yc @401866752
//   Ab @468713472 | woutT @472899584
// Aliases: x_bf @401866752 (dead after gemm1), wqkvT @201326592 (dead after gemm1),
//          attnb @268173312 (written after pyramid dead), Y0 = d_out (overwritten by gemm2).
extern "C" void kernel_launch(void* const* d_in, const int* in_sizes, int n_in,
                              void* d_out, int out_size, void* d_ws, size_t ws_size,
                              hipStream_t stream) {
  const float* x = (const float*)d_in[0];
  const float* wqkv = (const float*)d_in[1];
  const float* wout = (const float*)d_in[2];
  const float* bout = (const float*)d_in[3];
  float* out = (float*)d_out;
  (void)in_sizes; (void)n_in; (void)out_size; (void)ws_size;

  char* base = (char*)d_ws;
  bf16_t* C1    = (bf16_t*)(base + 0);
  bf16_t* Pq    = (bf16_t*)(base + 201326592);
  bf16_t* Pk    = (bf16_t*)(base + 268173312);
  bf16_t* Pv    = (bf16_t*)(base + 335020032);
  bf16_t* Yc    = (bf16_t*)(base + 401866752);
  float*  Ab    = (float*)(base + 468713472);
  bf16_t* woutT = (bf16_t*)(base + 472899584);
  bf16_t* x_bf  = (bf16_t*)(base + 401866752);
  bf16_t* wqkvT = (bf16_t*)(base + 201326592);
  bf16_t* attnb = (bf16_t*)(base + 268173312);
  float*  Y0    = out;

  cvt_f32_to_bf16<<<16384, 256, 0, stream>>>(x, x_bf);
  transpose_to_bf16<<<dim3(96, 32), 256, 0, stream>>>(wqkv, wqkvT, 1024, 3072);
  transpose_to_bf16<<<dim3(32, 32), 256, 0, stream>>>(wout, woutT, 1024, 1024);

  gemm256<0><<<1536, 512, 0, stream>>>(x_bf, wqkvT, (void*)C1, nullptr,
                                       32768, 3072, 1024, 3072, 12);

  coarsen1<<<8192, 256, 0, stream>>>(C1, Pq, Pk, Pv);
  coarsen_rest<<<512, 256, 0, stream>>>(Pq, Pk, Pv);
  attn_l0<<<32768, 256, 0, stream>>>(C1, Y0, Ab);
  attn_coarse_all<<<32640, 256, 0, stream>>>(Pq, Pk, Pv, Yc, Ab);
  combine_kernel<<<16384, 256, 0, stream>>>(Y0, Yc, Ab, attnb);

  gemm256<1><<<512, 512, 0, stream>>>(attnb, woutT, (void*)out, bout,
                                      32768, 1024, 1024, 1024, 4);
}

// Round 4
// 798.757 us; speedup vs baseline: 1.3731x; 1.3731x over previous
//
#include <hip/hip_runtime.h>
#include <hip/hip_bf16.h>

typedef __bf16 bf16_t;
typedef bf16_t bf16x8 __attribute__((ext_vector_type(8)));
typedef float f32x4 __attribute__((ext_vector_type(4)));

// ---------------------------------------------------------------- helpers
__device__ __forceinline__ void gl_lds16(const bf16_t* g, bf16_t* l) {
  __builtin_amdgcn_global_load_lds(
      (const __attribute__((address_space(1))) void*)g,
      (__attribute__((address_space(3))) void*)l,
      16, 0, 0);
}

__device__ __forceinline__ void load8f(const bf16_t* p, float* f) {
  bf16x8 v = *(const bf16x8*)p;
#pragma unroll
  for (int e = 0; e < 8; ++e) f[e] = (float)v[e];
}
__device__ __forceinline__ void store8f(bf16_t* p, const float* f) {
  bf16x8 v;
#pragma unroll
  for (int e = 0; e < 8; ++e) v[e] = (bf16_t)f[e];
  *(bf16x8*)p = v;
}

// ---------------------------------------------------------------- fp32 -> bf16 (x)
__global__ __launch_bounds__(256) void cvt_f32_to_bf16(const float* __restrict__ in,
                                                       bf16_t* __restrict__ o) {
  size_t gid = (size_t)blockIdx.x * 256 + threadIdx.x;
  const float4* p = (const float4*)in + gid * 2;
  float4 a = p[0], b = p[1];
  bf16x8 v;
  v[0] = (bf16_t)a.x; v[1] = (bf16_t)a.y; v[2] = (bf16_t)a.z; v[3] = (bf16_t)a.w;
  v[4] = (bf16_t)b.x; v[5] = (bf16_t)b.y; v[6] = (bf16_t)b.z; v[7] = (bf16_t)b.w;
  *(bf16x8*)(o + gid * 8) = v;
}

// ---------------------------------------------------------------- weight transpose + cast: w[K][N] -> wT[N][K] bf16
__global__ __launch_bounds__(256) void transpose_to_bf16(const float* __restrict__ w,
                                                         bf16_t* __restrict__ wT,
                                                         int K, int N) {
  __shared__ float t[32][33];
  int bx = blockIdx.x, by = blockIdx.y;
  int tx = threadIdx.x & 31, ty = threadIdx.x >> 5;
#pragma unroll
  for (int r = ty; r < 32; r += 8)
    t[r][tx] = w[(size_t)(by * 32 + r) * N + bx * 32 + tx];
  __syncthreads();
#pragma unroll
  for (int r = ty; r < 32; r += 8)
    wT[(size_t)(bx * 32 + r) * K + by * 32 + tx] = (bf16_t)t[tx][r];
}

// ---------------------------------------------------------------- 256x256 8-phase GEMM (T1+T2+T3+T4+T5)
// C[M][N] = A[M][K] @ Bt[N][K]^T.  8 waves (512 thr), BK=64, dbuf LDS 128 KiB,
// 4 phases/K-tile, counted vmcnt(6) at tile boundary only.
// T2: k-slot XOR swizzle (slot' = slot ^ (row&7)); gload_lds dest stays linear,
// the write-side permutation is applied to the GLOBAL source (rule #21), the
// read-side to the ds_read address. Both are the same involution.
// EPI 0: bf16 C.  EPI 1: fp32 C + bias.
template <int EPI>
__global__ __launch_bounds__(512, 2) void gemm256(const bf16_t* __restrict__ A,
                                                  const bf16_t* __restrict__ Bt,
                                                  void* __restrict__ Cp,
                                                  const float* __restrict__ bias,
                                                  int M, int N, int K, int ldc, int nTilesN) {
  __shared__ __align__(16) bf16_t As[2 * 256 * 64];   // [buf][256 rows][64 k]
  __shared__ __align__(16) bf16_t Bs[2 * 256 * 64];
  const int tid = threadIdx.x;
  const int w = tid >> 6, lane = tid & 63;

  // T1: bijective XCD swizzle (gridDim.x % 8 == 0), ntile-fast decode.
  int nwg = gridDim.x;
  int chunk = nwg >> 3;
  int wgid = (blockIdx.x & 7) * chunk + (blockIdx.x >> 3);
  int mt = wgid / nTilesN, ntile = wgid % nTilesN;
  const int bm = mt * 256, bn = ntile * 256;

  const int wr = w >> 2, wc = w & 3;          // 2x4 wave grid; wave tile 128x64
  const int lr = lane & 15, lg = lane >> 4;
  const int sw = lr & 7;                      // T2 read-side XOR key (row&7 == lr&7)
  const int nt = K >> 6;

  f32x4 acc[8][4] = {};

  // stage one half-tile (128 rows x 64 k = 16 KB): 2 gload_lds per wave.
  // lane's LDS slot (linear) = row (lane>>3), k-slot (lane&7); it must hold the
  // data of logical k-slot (lane&7)^(row&7) -> pre-swizzled global source.
  auto stageHalf = [&](const bf16_t* __restrict__ G, int rbase, int kt, int ld,
                       bf16_t* lbuf, int h) {
#pragma unroll
    for (int j = 0; j < 2; ++j) {
      int b = j * 8 + w;                                   // 16 chunk-blocks of 1 KB
      int r3 = lane >> 3;                                  // ldsrow & 7
      int k8 = (lane & 7) ^ r3;                            // T2 pre-swizzled source slot
      gl_lds16(G + (size_t)(rbase + h * 128 + b * 8 + r3) * ld + kt + k8 * 8,
               lbuf + h * 8192 + b * 512);                 // wave-uniform LDS base
    }
  };

  // prologue: tiles 0 and 1 fully staged
  stageHalf(Bt, bn, 0, K, Bs, 0); stageHalf(Bt, bn, 0, K, Bs, 1);
  stageHalf(A, bm, 0, K, As, 0);  stageHalf(A, bm, 0, K, As, 1);
  if (nt > 1) {
    stageHalf(Bt, bn, 64, K, Bs + 16384, 0); stageHalf(Bt, bn, 64, K, Bs + 16384, 1);
    stageHalf(A, bm, 64, K, As + 16384, 0);  stageHalf(A, bm, 64, K, As + 16384, 1);
    asm volatile("s_waitcnt vmcnt(8)" ::: "memory");       // tile 0 landed
  } else {
    asm volatile("s_waitcnt vmcnt(0)" ::: "memory");
  }
  __syncthreads();

  for (int t = 0; t < nt; ++t) {
    const int c = t & 1;
    bf16_t* Abuf = As + c * 16384;
    bf16_t* Bbuf = Bs + c * 16384;
    const bool pf = (t + 2) < nt;
    const int kt2 = (t + 2) << 6;
    bf16x8 bfrag[4][2];

#pragma unroll
    for (int p = 0; p < 4; ++p) {
      // ---- ds-loads for this phase (A rows 32p..32p+31 of the wave's half)
      bf16x8 afrag[2][2];
#pragma unroll
      for (int fi = 0; fi < 2; ++fi)
#pragma unroll
        for (int kk = 0; kk < 2; ++kk)
          afrag[fi][kk] = *(const bf16x8*)&Abuf[(wr * 128 + p * 32 + fi * 16 + lr) * 64 +
                                                (((kk * 4 + lg) ^ sw) * 8)];
      if (p == 0) {
#pragma unroll
        for (int fj = 0; fj < 4; ++fj)
#pragma unroll
          for (int kk = 0; kk < 2; ++kk)
            bfrag[fj][kk] = *(const bf16x8*)&Bbuf[(wc * 64 + fj * 16 + lr) * 64 +
                                                  (((kk * 4 + lg) ^ sw) * 8)];
      }
      // ---- stage tile t+2 into the buffer being drained (read-liveness safe order)
      if (pf) {
        if (p == 1) stageHalf(Bt, bn, kt2, K, Bbuf, 0);
        if (p == 2) stageHalf(Bt, bn, kt2, K, Bbuf, 1);
        if (p == 3) { stageHalf(A, bm, kt2, K, Abuf, 0); stageHalf(A, bm, kt2, K, Abuf, 1); }
      }
      __builtin_amdgcn_s_barrier();
      asm volatile("s_waitcnt lgkmcnt(0)" ::: "memory");
      __builtin_amdgcn_sched_barrier(0);
      __builtin_amdgcn_s_setprio(1);
#pragma unroll
      for (int kk = 0; kk < 2; ++kk)
#pragma unroll
        for (int fi = 0; fi < 2; ++fi)
#pragma unroll
          for (int fj = 0; fj < 4; ++fj)
            acc[p * 2 + fi][fj] = __builtin_amdgcn_mfma_f32_16x16x32_bf16(
                afrag[fi][kk], bfrag[fj][kk], acc[p * 2 + fi][fj], 0, 0, 0);
      __builtin_amdgcn_s_setprio(0);
      if (p == 3) {
        if (pf) asm volatile("s_waitcnt vmcnt(6)" ::: "memory");   // counted: tile t+1 landed
        else    asm volatile("s_waitcnt vmcnt(0)" ::: "memory");   // tail drain
      }
      __builtin_amdgcn_s_barrier();
    }
  }

#pragma unroll
  for (int fi = 0; fi < 8; ++fi)
#pragma unroll
    for (int fj = 0; fj < 4; ++fj)
#pragma unroll
      for (int r = 0; r < 4; ++r) {
        int row = bm + wr * 128 + fi * 16 + lg * 4 + r;
        int col = bn + wc * 64 + fj * 16 + lr;
        float v = acc[fi][fj][r];
        if (EPI == 0) ((bf16_t*)Cp)[(size_t)row * ldc + col] = (bf16_t)v;
        else          ((float*)Cp)[(size_t)row * ldc + col] = v + bias[col];
      }
}

// ---------------------------------------------------------------- pyramid coarsen level 1 (from C1)
__global__ __launch_bounds__(256) void coarsen1(const bf16_t* __restrict__ C1,
                                                bf16_t* __restrict__ Pq,
                                                bf16_t* __restrict__ Pk,
                                                bf16_t* __restrict__ Pv) {
  int gid = blockIdx.x * 256 + threadIdx.x;      // 64 hg * 4096 rows * 8 d8
  int d8 = gid & 7;
  int r = (gid >> 3) & 4095;
  int hg = gid >> 15;
  size_t base0 = ((size_t)(hg >> 4) * 8192 + 2 * r) * 3072 + (hg & 15) * 64 + d8 * 8;
  size_t base1 = base0 + 3072;
  float q0[8], q1[8], k0[8], k1[8], v0[8], v1[8], t[8];
  load8f(C1 + base0, q0);        load8f(C1 + base1, q1);
  load8f(C1 + base0 + 1024, k0); load8f(C1 + base1 + 1024, k1);
  load8f(C1 + base0 + 2048, v0); load8f(C1 + base1 + 2048, v1);
  size_t o = ((size_t)hg * 8160 + r) * 64 + d8 * 8;
#pragma unroll
  for (int e = 0; e < 8; ++e) t[e] = 0.5f * (q0[e] + q1[e]);
  store8f(Pq + o, t);
#pragma unroll
  for (int e = 0; e < 8; ++e) t[e] = 0.5f * (k0[e] + k1[e]);
  store8f(Pk + o, t);
#pragma unroll
  for (int e = 0; e < 8; ++e) t[e] = v0[e] + v1[e];
  store8f(Pv + o, t);
}

// ---------------------------------------------------------------- pyramid coarsen level l>=2 (d8 innermost: coalesced)
__global__ __launch_bounds__(256) void coarsen_lvl(bf16_t* __restrict__ Pq,
                                                   bf16_t* __restrict__ Pk,
                                                   bf16_t* __restrict__ Pv,
                                                   int mshift, int poffIn, int poffOut) {
  int gid = blockIdx.x * 256 + threadIdx.x;
  int d8 = gid & 7;
  int r = (gid >> 3) & ((1 << mshift) - 1);
  int hg = gid >> (3 + mshift);
  if (hg >= 64) return;
  size_t b0 = ((size_t)hg * 8160 + poffIn + 2 * r) * 64 + d8 * 8;
  size_t b1 = b0 + 64;
  size_t o = ((size_t)hg * 8160 + poffOut + r) * 64 + d8 * 8;
  float a0[8], a1[8], t[8];
  load8f(Pq + b0, a0); load8f(Pq + b1, a1);
#pragma unroll
  for (int e = 0; e < 8; ++e) t[e] = 0.5f * (a0[e] + a1[e]);
  store8f(Pq + o, t);
  load8f(Pk + b0, a0); load8f(Pk + b1, a1);
#pragma unroll
  for (int e = 0; e < 8; ++e) t[e] = 0.5f * (a0[e] + a1[e]);
  store8f(Pk + o, t);
  load8f(Pv + b0, a0); load8f(Pv + b1, a1);
#pragma unroll
  for (int e = 0; e < 8; ++e) t[e] = a0[e] + a1[e];
  store8f(Pv + o, t);
}

// ---------------------------------------------------------------- per-level 16x16 block attention, finest level
__global__ __launch_bounds__(256) void attn_l0(const bf16_t* __restrict__ C1,
                                               float* __restrict__ Y0,
                                               float* __restrict__ Asum) {
  __shared__ float qs[16 * 64], ks[16 * 65], vs[16 * 64], SA[16 * 17];
  const int tid = threadIdx.x;
  const int blk = blockIdx.x & 511;
  const int hg = blockIdx.x >> 9;

  for (int c = tid; c < 384; c += 256) {
    int tns = c >> 7;
    int idx = c & 127;
    int i = idx >> 3, d8 = idx & 7;
    int t = blk * 16 + i;
    const bf16_t* src = C1 + ((size_t)(hg >> 4) * 8192 + t) * 3072 + (hg & 15) * 64 + tns * 1024 + d8 * 8;
    bf16x8 v = *(const bf16x8*)src;
    float* dst = (tns == 0) ? &qs[i * 64 + d8 * 8]
                            : (tns == 1 ? &ks[i * 65 + d8 * 8] : &vs[i * 64 + d8 * 8]);
#pragma unroll
    for (int e = 0; e < 8; ++e) dst[e] = (float)v[e];
  }
  __syncthreads();

  const int i = tid >> 4, j = tid & 15;
  float s = 0.f;
#pragma unroll
  for (int d = 0; d < 64; ++d) s += qs[i * 64 + d] * ks[j * 65 + d];
  s *= 0.125f;
  float mx = s;
#pragma unroll
  for (int m = 8; m >= 1; m >>= 1) mx = fmaxf(mx, __shfl_xor(mx, m, 64));
  float a = expf(s - mx);
  float as = a;
#pragma unroll
  for (int m = 8; m >= 1; m >>= 1) as += __shfl_xor(as, m, 64);
  SA[i * 17 + j] = a;
  if (j == 0) Asum[(size_t)hg * 16352 + blk * 16 + i] = as;
  __syncthreads();

#pragma unroll
  for (int e = 0; e < 4; ++e) {
    int idx = tid + e * 256;
    int ii = idx >> 6, d = idx & 63;
    float y = 0.f;
#pragma unroll
    for (int jj = 0; jj < 16; ++jj) y += SA[ii * 17 + jj] * vs[jj * 64 + d];
    Y0[((size_t)hg * 8192 + blk * 16 + ii) * 64 + d] = y;
  }
}

// all coarse levels (1..8) fused in one dispatch; 32640 workgroups
__global__ __launch_bounds__(256) void attn_coarse_all(const bf16_t* __restrict__ Pq,
                                                       const bf16_t* __restrict__ Pk,
                                                       const bf16_t* __restrict__ Pv,
                                                       bf16_t* __restrict__ Yc,
                                                       float* __restrict__ Asum) {
  __shared__ float qs[16 * 64], ks[16 * 65], vs[16 * 64], SA[16 * 17];
  const int poffA[9] = {0, 0, 4096, 6144, 7168, 7680, 7936, 8064, 8128};
  const int aoffA[9] = {0, 8192, 12288, 14336, 15360, 15872, 16128, 16256, 16320};
  int bid = blockIdx.x, l = 1, cnt = 16384;
  while (bid >= cnt) { bid -= cnt; cnt >>= 1; ++l; }
  const int lg2nblk = 9 - l;
  const int blk = bid & ((1 << lg2nblk) - 1);
  const int hg = bid >> lg2nblk;
  const int kvblk = blk ^ 1;
  const int poff = poffA[l], aoff = aoffA[l];
  const int tid = threadIdx.x;

  for (int c = tid; c < 384; c += 256) {
    int tns = c >> 7;
    int idx = c & 127;
    int i = idx >> 3, d8 = idx & 7;
    int t = ((tns == 0) ? blk : kvblk) * 16 + i;
    const bf16_t* P = (tns == 0) ? Pq : (tns == 1 ? Pk : Pv);
    const bf16_t* src = P + ((size_t)hg * 8160 + poff + t) * 64 + d8 * 8;
    bf16x8 v = *(const bf16x8*)src;
    float* dst = (tns == 0) ? &qs[i * 64 + d8 * 8]
                            : (tns == 1 ? &ks[i * 65 + d8 * 8] : &vs[i * 64 + d8 * 8]);
#pragma unroll
    for (int e = 0; e < 8; ++e) dst[e] = (float)v[e];
  }
  __syncthreads();

  const int i = tid >> 4, j = tid & 15;
  float s = 0.f;
#pragma unroll
  for (int d = 0; d < 64; ++d) s += qs[i * 64 + d] * ks[j * 65 + d];
  s *= 0.125f;
  float mx = s;
#pragma unroll
  for (int m = 8; m >= 1; m >>= 1) mx = fmaxf(mx, __shfl_xor(mx, m, 64));
  float a = expf(s - mx);
  float as = a;
#pragma unroll
  for (int m = 8; m >= 1; m >>= 1) as += __shfl_xor(as, m, 64);
  SA[i * 17 + j] = a;
  if (j == 0) Asum[(size_t)hg * 16352 + aoff + blk * 16 + i] = as;
  __syncthreads();

#pragma unroll
  for (int e = 0; e < 4; ++e) {
    int idx = tid + e * 256;
    int ii = idx >> 6, d = idx & 63;
    float y = 0.f;
#pragma unroll
    for (int jj = 0; jj < 16; ++jj) y += SA[ii * 17 + jj] * vs[jj * 64 + d];
    Yc[((size_t)hg * 8160 + poff + blk * 16 + ii) * 64 + d] = (bf16_t)y;
  }
}

// ---------------------------------------------------------------- combine levels + normalize -> attn bf16 [32768][1024]
__global__ __launch_bounds__(256) void combine_kernel(const float* __restrict__ Y0,
                                                      const bf16_t* __restrict__ Yc,
                                                      const float* __restrict__ As,
                                                      bf16_t* __restrict__ attnb) {
  int gid = blockIdx.x * 256 + threadIdx.x;
  int d8 = gid & 7;
  int t = (gid >> 3) & 8191;
  int hg = gid >> 16;
  const int poffA[9] = {0, 0, 4096, 6144, 7168, 7680, 7936, 8064, 8128};
  const int aoffA[9] = {0, 8192, 12288, 14336, 15360, 15872, 16128, 16256, 16320};
  float acc[8];
  float asum = As[(size_t)hg * 16352 + t];
  {
    const float4* yp = (const float4*)(Y0 + ((size_t)hg * 8192 + t) * 64 + d8 * 8);
    float4 y0 = yp[0], y1 = yp[1];
    acc[0] = y0.x; acc[1] = y0.y; acc[2] = y0.z; acc[3] = y0.w;
    acc[4] = y1.x; acc[5] = y1.y; acc[6] = y1.z; acc[7] = y1.w;
  }
#pragma unroll
  for (int l = 1; l < 9; ++l) {
    int rc = t >> l;
    asum += As[(size_t)hg * 16352 + aoffA[l] + rc];
    bf16x8 v = *(const bf16x8*)(Yc + ((size_t)hg * 8160 + poffA[l] + rc) * 64 + d8 * 8);
#pragma unroll
    for (int e = 0; e < 8; ++e) acc[e] += (float)v[e];
  }
  float inv = 1.f / (asum + 1e-8f);
  bf16x8 v;
#pragma unroll
  for (int e = 0; e < 8; ++e) v[e] = (bf16_t)(acc[e] * inv);
  *(bf16x8*)(attnb + ((size_t)(hg >> 4) * 8192 + t) * 1024 + (hg & 15) * 64 + d8 * 8) = v;
}

// ---------------------------------------------------------------- launch
// Workspace plan (bytes), total ~453 MiB (same as passing round-2/3 layout):
//   C1 @0 (192M) | Pq @201326592 | Pk @268173312 | Pv @335020032 | Yc @401866752
//   Ab @468713472 | woutT @472899584
// Aliases: x_bf @401866752 (dead after gemm1), wqkvT @201326592 (dead after gemm1),
//          attnb @268173312 (written after pyramid dead), Y0 = d_out (overwritten by gemm2).
extern "C" void kernel_launch(void* const* d_in, const int* in_sizes, int n_in,
                              void* d_out, int out_size, void* d_ws, size_t ws_size,
                              hipStream_t stream) {
  const float* x = (const float*)d_in[0];
  const float* wqkv = (const float*)d_in[1];
  const float* wout = (const float*)d_in[2];
  const float* bout = (const float*)d_in[3];
  float* out = (float*)d_out;
  (void)in_sizes; (void)n_in; (void)out_size; (void)ws_size;

  char* base = (char*)d_ws;
  bf16_t* C1    = (bf16_t*)(base + 0);
  bf16_t* Pq    = (bf16_t*)(base + 201326592);
  bf16_t* Pk    = (bf16_t*)(base + 268173312);
  bf16_t* Pv    = (bf16_t*)(base + 335020032);
  bf16_t* Yc    = (bf16_t*)(base + 401866752);
  float*  Ab    = (float*)(base + 468713472);
  bf16_t* woutT = (bf16_t*)(base + 472899584);
  bf16_t* x_bf  = (bf16_t*)(base + 401866752);
  bf16_t* wqkvT = (bf16_t*)(base + 201326592);
  bf16_t* attnb = (bf16_t*)(base + 268173312);
  float*  Y0    = out;

  cvt_f32_to_bf16<<<16384, 256, 0, stream>>>(x, x_bf);
  transpose_to_bf16<<<dim3(96, 32), 256, 0, stream>>>(wqkv, wqkvT, 1024, 3072);
  transpose_to_bf16<<<dim3(32, 32), 256, 0, stream>>>(wout, woutT, 1024, 1024);

  gemm256<0><<<1536, 512, 0, stream>>>(x_bf, wqkvT, (void*)C1, nullptr,
                                       32768, 3072, 1024, 3072, 12);

  static const int poffA[9] = {0, 0, 4096, 6144, 7168, 7680, 7936, 8064, 8128};

  coarsen1<<<8192, 256, 0, stream>>>(C1, Pq, Pk, Pv);
  for (int l = 2; l <= 8; ++l) {
    int mshift = 13 - l;
    coarsen_lvl<<<2 << mshift, 256, 0, stream>>>(Pq, Pk, Pv, mshift, poffA[l - 1], poffA[l]);
  }
  attn_l0<<<32768, 256, 0, stream>>>(C1, Y0, Ab);
  attn_coarse_all<<<32640, 256, 0, stream>>>(Pq, Pk, Pv, Yc, Ab);
  combine_kernel<<<16384, 256, 0, stream>>>(Y0, Yc, Ab, attnb);

  gemm256<1><<<512, 512, 0, stream>>>(attnb, woutT, (void*)out, bout,
                                      32768, 1024, 1024, 1024, 4);
}

// Round 5
// 790.154 us; speedup vs baseline: 1.3880x; 1.0109x over previous
//
#include <hip/hip_runtime.h>
#include <hip/hip_bf16.h>

typedef __bf16 bf16_t;
typedef bf16_t bf16x8 __attribute__((ext_vector_type(8)));
typedef float f32x4 __attribute__((ext_vector_type(4)));

// Pyramid layout: P[hg][16352][64] bf16, hg = b*16+h (64 head-groups).
// Row offsets per level l (rows per hg = 8192>>l):
//   {0, 8192, 12288, 14336, 15360, 15872, 16128, 16256, 16320}, total 16352.
#define PROWS 16352

// ---------------------------------------------------------------- helpers
__device__ __forceinline__ void gl_lds16(const bf16_t* g, bf16_t* l) {
  __builtin_amdgcn_global_load_lds(
      (const __attribute__((address_space(1))) void*)g,
      (__attribute__((address_space(3))) void*)l,
      16, 0, 0);
}

__device__ __forceinline__ void load8f(const bf16_t* p, float* f) {
  bf16x8 v = *(const bf16x8*)p;
#pragma unroll
  for (int e = 0; e < 8; ++e) f[e] = (float)v[e];
}
__device__ __forceinline__ void store8f(bf16_t* p, const float* f) {
  bf16x8 v;
#pragma unroll
  for (int e = 0; e < 8; ++e) v[e] = (bf16_t)f[e];
  *(bf16x8*)p = v;
}

// ---------------------------------------------------------------- fp32 -> bf16 (x)
__global__ __launch_bounds__(256) void cvt_f32_to_bf16(const float* __restrict__ in,
                                                       bf16_t* __restrict__ o) {
  size_t gid = (size_t)blockIdx.x * 256 + threadIdx.x;
  const float4* p = (const float4*)in + gid * 2;
  float4 a = p[0], b = p[1];
  bf16x8 v;
  v[0] = (bf16_t)a.x; v[1] = (bf16_t)a.y; v[2] = (bf16_t)a.z; v[3] = (bf16_t)a.w;
  v[4] = (bf16_t)b.x; v[5] = (bf16_t)b.y; v[6] = (bf16_t)b.z; v[7] = (bf16_t)b.w;
  *(bf16x8*)(o + gid * 8) = v;
}

// ---------------------------------------------------------------- weight transpose + cast: w[K][N] -> wT[N][K] bf16
__global__ __launch_bounds__(256) void transpose_to_bf16(const float* __restrict__ w,
                                                         bf16_t* __restrict__ wT,
                                                         int K, int N) {
  __shared__ float t[32][33];
  int bx = blockIdx.x, by = blockIdx.y;
  int tx = threadIdx.x & 31, ty = threadIdx.x >> 5;
#pragma unroll
  for (int r = ty; r < 32; r += 8)
    t[r][tx] = w[(size_t)(by * 32 + r) * N + bx * 32 + tx];
  __syncthreads();
#pragma unroll
  for (int r = ty; r < 32; r += 8)
    wT[(size_t)(bx * 32 + r) * K + by * 32 + tx] = (bf16_t)t[tx][r];
}

// ---------------------------------------------------------------- 256x256 8-phase GEMM (T1+T2+T3+T4+T5)
// C[M][N] = A[M][K] @ Bt[N][K]^T.  8 waves (512 thr), BK=64, dbuf LDS 128 KiB,
// 4 phases/K-tile, counted vmcnt(8) at tile boundary only.
// T2: k-slot XOR swizzle; gload_lds dest linear, write-perm on GLOBAL source,
// read-perm on ds_read address (same involution, rule #21).
// EPI 0: scatter bf16 into pyramid P (qkv de-interleave, q scaled 0.125).
// EPI 1: fp32 C + bias.
template <int EPI>
__global__ __launch_bounds__(512, 2) void gemm256(const bf16_t* __restrict__ A,
                                                  const bf16_t* __restrict__ Bt,
                                                  float* __restrict__ Cp,
                                                  const float* __restrict__ bias,
                                                  bf16_t* __restrict__ Pq,
                                                  bf16_t* __restrict__ Pk,
                                                  bf16_t* __restrict__ Pv,
                                                  int M, int N, int K, int ldc, int nTilesN) {
  __shared__ __align__(16) bf16_t As[2 * 256 * 64];
  __shared__ __align__(16) bf16_t Bs[2 * 256 * 64];
  const int tid = threadIdx.x;
  const int w = tid >> 6, lane = tid & 63;

  // T1: bijective XCD swizzle (gridDim.x % 8 == 0), ntile-fast decode.
  int nwg = gridDim.x;
  int chunk = nwg >> 3;
  int wgid = (blockIdx.x & 7) * chunk + (blockIdx.x >> 3);
  int mt = wgid / nTilesN, ntile = wgid % nTilesN;
  const int bm = mt * 256, bn = ntile * 256;

  const int wr = w >> 2, wc = w & 3;          // 2x4 wave grid; wave tile 128x64
  const int lr = lane & 15, lg = lane >> 4;
  const int sw = lr & 7;                      // T2 read-side XOR key
  const int nt = K >> 6;

  f32x4 acc[8][4] = {};

  auto stageHalf = [&](const bf16_t* __restrict__ G, int rbase, int kt, int ld,
                       bf16_t* lbuf, int h) {
#pragma unroll
    for (int j = 0; j < 2; ++j) {
      int b = j * 8 + w;
      int r3 = lane >> 3;
      int k8 = (lane & 7) ^ r3;               // T2 pre-swizzled source slot
      gl_lds16(G + (size_t)(rbase + h * 128 + b * 8 + r3) * ld + kt + k8 * 8,
               lbuf + h * 8192 + b * 512);
    }
  };

  // prologue: tiles 0 and 1 fully staged
  stageHalf(Bt, bn, 0, K, Bs, 0); stageHalf(Bt, bn, 0, K, Bs, 1);
  stageHalf(A, bm, 0, K, As, 0);  stageHalf(A, bm, 0, K, As, 1);
  if (nt > 1) {
    stageHalf(Bt, bn, 64, K, Bs + 16384, 0); stageHalf(Bt, bn, 64, K, Bs + 16384, 1);
    stageHalf(A, bm, 64, K, As + 16384, 0);  stageHalf(A, bm, 64, K, As + 16384, 1);
    asm volatile("s_waitcnt vmcnt(8)" ::: "memory");
  } else {
    asm volatile("s_waitcnt vmcnt(0)" ::: "memory");
  }
  __syncthreads();

  for (int t = 0; t < nt; ++t) {
    const int c = t & 1;
    bf16_t* Abuf = As + c * 16384;
    bf16_t* Bbuf = Bs + c * 16384;
    const bool pf = (t + 2) < nt;
    const int kt2 = (t + 2) << 6;
    bf16x8 bfrag[4][2];

#pragma unroll
    for (int p = 0; p < 4; ++p) {
      bf16x8 afrag[2][2];
#pragma unroll
      for (int fi = 0; fi < 2; ++fi)
#pragma unroll
        for (int kk = 0; kk < 2; ++kk)
          afrag[fi][kk] = *(const bf16x8*)&Abuf[(wr * 128 + p * 32 + fi * 16 + lr) * 64 +
                                                (((kk * 4 + lg) ^ sw) * 8)];
      if (p == 0) {
#pragma unroll
        for (int fj = 0; fj < 4; ++fj)
#pragma unroll
          for (int kk = 0; kk < 2; ++kk)
            bfrag[fj][kk] = *(const bf16x8*)&Bbuf[(wc * 64 + fj * 16 + lr) * 64 +
                                                  (((kk * 4 + lg) ^ sw) * 8)];
      }
      if (pf) {
        if (p == 1) stageHalf(Bt, bn, kt2, K, Bbuf, 0);
        if (p == 2) stageHalf(Bt, bn, kt2, K, Bbuf, 1);
        if (p == 3) { stageHalf(A, bm, kt2, K, Abuf, 0); stageHalf(A, bm, kt2, K, Abuf, 1); }
      }
      __builtin_amdgcn_s_barrier();
      asm volatile("s_waitcnt lgkmcnt(0)" ::: "memory");
      __builtin_amdgcn_sched_barrier(0);
      __builtin_amdgcn_s_setprio(1);
#pragma unroll
      for (int kk = 0; kk < 2; ++kk)
#pragma unroll
        for (int fi = 0; fi < 2; ++fi)
#pragma unroll
          for (int fj = 0; fj < 4; ++fj)
            acc[p * 2 + fi][fj] = __builtin_amdgcn_mfma_f32_16x16x32_bf16(
                afrag[fi][kk], bfrag[fj][kk], acc[p * 2 + fi][fj], 0, 0, 0);
      __builtin_amdgcn_s_setprio(0);
      if (p == 3) {
        if (pf) asm volatile("s_waitcnt vmcnt(8)" ::: "memory");   // t+1 fully landed
        else    asm volatile("s_waitcnt vmcnt(0)" ::: "memory");   // tail drain
      }
      __builtin_amdgcn_s_barrier();
    }
  }

#pragma unroll
  for (int fi = 0; fi < 8; ++fi)
#pragma unroll
    for (int fj = 0; fj < 4; ++fj)
#pragma unroll
      for (int r = 0; r < 4; ++r) {
        int row = bm + wr * 128 + fi * 16 + lg * 4 + r;
        int col = bn + wc * 64 + fj * 16 + lr;
        float v = acc[fi][fj][r];
        if (EPI == 0) {
          // scatter into pyramid level 0: col -> (tns, head, d)
          int tns = col >> 10, col10 = col & 1023;
          int h = col10 >> 6, d = col10 & 63;
          int hg = (row >> 13) * 16 + h;
          int trow = row & 8191;
          if (tns == 0) v *= 0.125f;          // q pre-scale (DIM_HEAD^-0.5)
          bf16_t* Pt = (tns == 0) ? Pq : (tns == 1 ? Pk : Pv);
          Pt[((size_t)hg * PROWS + trow) * 64 + d] = (bf16_t)v;
        } else {
          Cp[(size_t)row * ldc + col] = v + bias[col];
        }
      }
}

// ---------------------------------------------------------------- pyramid coarsen level l>=1 (d8 innermost: coalesced)
__global__ __launch_bounds__(256) void coarsen_lvl(bf16_t* __restrict__ Pq,
                                                   bf16_t* __restrict__ Pk,
                                                   bf16_t* __restrict__ Pv,
                                                   int mshift, int poffIn, int poffOut) {
  int gid = blockIdx.x * 256 + threadIdx.x;
  int d8 = gid & 7;
  int r = (gid >> 3) & ((1 << mshift) - 1);
  int hg = gid >> (3 + mshift);
  if (hg >= 64) return;
  size_t b0 = ((size_t)hg * PROWS + poffIn + 2 * r) * 64 + d8 * 8;
  size_t b1 = b0 + 64;
  size_t o = ((size_t)hg * PROWS + poffOut + r) * 64 + d8 * 8;
  float a0[8], a1[8], t[8];
  load8f(Pq + b0, a0); load8f(Pq + b1, a1);
#pragma unroll
  for (int e = 0; e < 8; ++e) t[e] = 0.5f * (a0[e] + a1[e]);
  store8f(Pq + o, t);
  load8f(Pk + b0, a0); load8f(Pk + b1, a1);
#pragma unroll
  for (int e = 0; e < 8; ++e) t[e] = 0.5f * (a0[e] + a1[e]);
  store8f(Pk + o, t);
  load8f(Pv + b0, a0); load8f(Pv + b1, a1);
#pragma unroll
  for (int e = 0; e < 8; ++e) t[e] = a0[e] + a1[e];
  store8f(Pv + o, t);
}

// ---------------------------------------------------------------- all-level 16x16 block attention (one dispatch)
// Levels 0..8. q pre-scaled in gemm1. Writes y (bf16) IN PLACE over the dead q
// rows of Pq (each block reads only its own q rows, then overwrites them; K/V
// partner rows live in Pk/Pv which are never written -> no cross-block hazard).
__global__ __launch_bounds__(256) void attn_all(bf16_t* __restrict__ Pq,
                                                const bf16_t* __restrict__ Pk,
                                                const bf16_t* __restrict__ Pv,
                                                float* __restrict__ Asum) {
  __shared__ float qs[16 * 64], ks[16 * 65], vs[16 * 64], SA[16 * 17];
  const int poffA[9] = {0, 8192, 12288, 14336, 15360, 15872, 16128, 16256, 16320};
  int bid = blockIdx.x, l = 0, cnt = 32768;
  while (bid >= cnt) { bid -= cnt; cnt >>= 1; ++l; }
  const int lg2nblk = 9 - l;
  const int blk = bid & ((1 << lg2nblk) - 1);
  const int hg = bid >> lg2nblk;
  const int kvblk = l ? (blk ^ 1) : blk;
  const int poff = poffA[l];
  const int tid = threadIdx.x;

  for (int c = tid; c < 384; c += 256) {
    int tns = c >> 7;
    int idx = c & 127;
    int i = idx >> 3, d8 = idx & 7;
    int t = ((tns == 0) ? blk : kvblk) * 16 + i;
    const bf16_t* P = (tns == 0) ? Pq : (tns == 1 ? Pk : Pv);
    const bf16_t* src = P + ((size_t)hg * PROWS + poff + t) * 64 + d8 * 8;
    bf16x8 v = *(const bf16x8*)src;
    float* dst = (tns == 0) ? &qs[i * 64 + d8 * 8]
                            : (tns == 1 ? &ks[i * 65 + d8 * 8] : &vs[i * 64 + d8 * 8]);
#pragma unroll
    for (int e = 0; e < 8; ++e) dst[e] = (float)v[e];
  }
  __syncthreads();

  const int i = tid >> 4, j = tid & 15;
  float s = 0.f;
#pragma unroll
  for (int d = 0; d < 64; ++d) s += qs[i * 64 + d] * ks[j * 65 + d];
  float mx = s;
#pragma unroll
  for (int m = 8; m >= 1; m >>= 1) mx = fmaxf(mx, __shfl_xor(mx, m, 64));
  float a = expf(s - mx);
  float as = a;
#pragma unroll
  for (int m = 8; m >= 1; m >>= 1) as += __shfl_xor(as, m, 64);
  SA[i * 17 + j] = a;
  if (j == 0) Asum[(size_t)hg * PROWS + poff + blk * 16 + i] = as;
  __syncthreads();

#pragma unroll
  for (int e = 0; e < 4; ++e) {
    int idx = tid + e * 256;
    int ii = idx >> 6, d = idx & 63;
    float y = 0.f;
#pragma unroll
    for (int jj = 0; jj < 16; ++jj) y += SA[ii * 17 + jj] * vs[jj * 64 + d];
    Pq[((size_t)hg * PROWS + poff + blk * 16 + ii) * 64 + d] = (bf16_t)y;
  }
}

// ---------------------------------------------------------------- combine levels + normalize -> attn bf16 [32768][1024]
__global__ __launch_bounds__(256) void combine_kernel(const bf16_t* __restrict__ Py,
                                                      const float* __restrict__ As,
                                                      bf16_t* __restrict__ attnb) {
  int gid = blockIdx.x * 256 + threadIdx.x;
  int d8 = gid & 7;
  int t = (gid >> 3) & 8191;
  int hg = gid >> 16;
  const int poffA[9] = {0, 8192, 12288, 14336, 15360, 15872, 16128, 16256, 16320};
  float acc[8] = {};
  float asum = 0.f;
#pragma unroll
  for (int l = 0; l < 9; ++l) {
    int rc = t >> l;
    size_t row = (size_t)hg * PROWS + poffA[l] + rc;
    asum += As[row];
    bf16x8 v = *(const bf16x8*)(Py + row * 64 + d8 * 8);
#pragma unroll
    for (int e = 0; e < 8; ++e) acc[e] += (float)v[e];
  }
  float inv = 1.f / (asum + 1e-8f);
  bf16x8 v;
#pragma unroll
  for (int e = 0; e < 8; ++e) v[e] = (bf16_t)(acc[e] * inv);
  *(bf16x8*)(attnb + ((size_t)(hg >> 4) * 8192 + t) * 1024 + (hg & 15) * 64 + d8 * 8) = v;
}

// ---------------------------------------------------------------- launch
// Workspace (bytes), total 481,550,336 (~459.2 MiB):
//   Pq @ 0           127.75 MiB  [64][16352][64] bf16 (lvl0 q -> y in place)
//   Pk @ 133955584   127.75 MiB
//   Pv @ 267911168   127.75 MiB
//   Ab @ 401866752   4 MiB       [64][16352] f32 Asum
//   woutT @ 406052864  2 MiB
//   x_bf @ 408150016  64 MiB     (dead after gemm1)
//   wqkvT @ 475258880 6 MiB      (dead after gemm1)
// Alias: attnb @ 133955584 over Pk (Pk dead after attn_all; combine writes it).
extern "C" void kernel_launch(void* const* d_in, const int* in_sizes, int n_in,
                              void* d_out, int out_size, void* d_ws, size_t ws_size,
                              hipStream_t stream) {
  const float* x = (const float*)d_in[0];
  const float* wqkv = (const float*)d_in[1];
  const float* wout = (const float*)d_in[2];
  const float* bout = (const float*)d_in[3];
  float* out = (float*)d_out;
  (void)in_sizes; (void)n_in; (void)out_size; (void)ws_size;

  char* base = (char*)d_ws;
  bf16_t* Pq    = (bf16_t*)(base + 0);
  bf16_t* Pk    = (bf16_t*)(base + 133955584);
  bf16_t* Pv    = (bf16_t*)(base + 267911168);
  float*  Ab    = (float*)(base + 401866752);
  bf16_t* woutT = (bf16_t*)(base + 406052864);
  bf16_t* x_bf  = (bf16_t*)(base + 408150016);
  bf16_t* wqkvT = (bf16_t*)(base + 475258880);
  bf16_t* attnb = (bf16_t*)(base + 133955584);   // alias over Pk

  cvt_f32_to_bf16<<<16384, 256, 0, stream>>>(x, x_bf);
  transpose_to_bf16<<<dim3(96, 32), 256, 0, stream>>>(wqkv, wqkvT, 1024, 3072);
  transpose_to_bf16<<<dim3(32, 32), 256, 0, stream>>>(wout, woutT, 1024, 1024);

  // qkv GEMM -> scatter directly into pyramid level 0 (q scaled)
  gemm256<0><<<1536, 512, 0, stream>>>(x_bf, wqkvT, nullptr, nullptr, Pq, Pk, Pv,
                                       32768, 3072, 1024, 3072, 12);

  static const int poffA[9] = {0, 8192, 12288, 14336, 15360, 15872, 16128, 16256, 16320};
  for (int l = 1; l <= 8; ++l) {
    int mshift = 13 - l;
    coarsen_lvl<<<2 << mshift, 256, 0, stream>>>(Pq, Pk, Pv, mshift, poffA[l - 1], poffA[l]);
  }

  attn_all<<<65408, 256, 0, stream>>>(Pq, Pk, Pv, Ab);
  combine_kernel<<<16384, 256, 0, stream>>>(Pq, Ab, attnb);

  gemm256<1><<<512, 512, 0, stream>>>(attnb, woutT, out, bout, nullptr, nullptr, nullptr,
                                      32768, 1024, 1024, 1024, 4);
}

// Round 6
// 648.171 us; speedup vs baseline: 1.6921x; 1.2191x over previous
//
#include <hip/hip_runtime.h>
#include <hip/hip_bf16.h>

typedef __bf16 bf16_t;
typedef bf16_t bf16x8 __attribute__((ext_vector_type(8)));
typedef float f32x4 __attribute__((ext_vector_type(4)));

// Pyramid layout: P[hg][16352][64] bf16, hg = b*16+h (64 head-groups).
// Row offsets per level l (rows per hg = 8192>>l):
//   {0, 8192, 12288, 14336, 15360, 15872, 16128, 16256, 16320}, total 16352.
#define PROWS 16352

// ---------------------------------------------------------------- helpers
__device__ __forceinline__ void gl_lds16(const bf16_t* g, bf16_t* l) {
  __builtin_amdgcn_global_load_lds(
      (const __attribute__((address_space(1))) void*)g,
      (__attribute__((address_space(3))) void*)l,
      16, 0, 0);
}

__device__ __forceinline__ void load8f(const bf16_t* p, float* f) {
  bf16x8 v = *(const bf16x8*)p;
#pragma unroll
  for (int e = 0; e < 8; ++e) f[e] = (float)v[e];
}
__device__ __forceinline__ void store8f(bf16_t* p, const float* f) {
  bf16x8 v;
#pragma unroll
  for (int e = 0; e < 8; ++e) v[e] = (bf16_t)f[e];
  *(bf16x8*)p = v;
}

// ---------------------------------------------------------------- fp32 -> bf16 (x)
__global__ __launch_bounds__(256) void cvt_f32_to_bf16(const float* __restrict__ in,
                                                       bf16_t* __restrict__ o) {
  size_t gid = (size_t)blockIdx.x * 256 + threadIdx.x;
  const float4* p = (const float4*)in + gid * 2;
  float4 a = p[0], b = p[1];
  bf16x8 v;
  v[0] = (bf16_t)a.x; v[1] = (bf16_t)a.y; v[2] = (bf16_t)a.z; v[3] = (bf16_t)a.w;
  v[4] = (bf16_t)b.x; v[5] = (bf16_t)b.y; v[6] = (bf16_t)b.z; v[7] = (bf16_t)b.w;
  *(bf16x8*)(o + gid * 8) = v;
}

// ---------------------------------------------------------------- weight transpose + cast: w[K][N] -> wT[N][K] bf16
__global__ __launch_bounds__(256) void transpose_to_bf16(const float* __restrict__ w,
                                                         bf16_t* __restrict__ wT,
                                                         int K, int N) {
  __shared__ float t[32][33];
  int bx = blockIdx.x, by = blockIdx.y;
  int tx = threadIdx.x & 31, ty = threadIdx.x >> 5;
#pragma unroll
  for (int r = ty; r < 32; r += 8)
    t[r][tx] = w[(size_t)(by * 32 + r) * N + bx * 32 + tx];
  __syncthreads();
#pragma unroll
  for (int r = ty; r < 32; r += 8)
    wT[(size_t)(bx * 32 + r) * K + by * 32 + tx] = (bf16_t)t[tx][r];
}

// ---------------------------------------------------------------- 256x256 8-phase GEMM (T1+T2+T3+T4+T5)
// C[M][N] = A[M][K] @ Bt[N][K]^T.  8 waves (512 thr), BK=64, dbuf LDS 128 KiB,
// 4 phases/K-tile, counted vmcnt(8) at tile boundary only.
// T2: k-slot XOR swizzle; gload_lds dest linear, write-perm on GLOBAL source,
// read-perm on ds_read address (same involution, rule #21).
// EPI 0: scatter bf16 into pyramid P (qkv de-interleave, q scaled 0.125).
// EPI 1: fp32 C + bias.
template <int EPI>
__global__ __launch_bounds__(512, 2) void gemm256(const bf16_t* __restrict__ A,
                                                  const bf16_t* __restrict__ Bt,
                                                  float* __restrict__ Cp,
                                                  const float* __restrict__ bias,
                                                  bf16_t* __restrict__ Pq,
                                                  bf16_t* __restrict__ Pk,
                                                  bf16_t* __restrict__ Pv,
                                                  int M, int N, int K, int ldc, int nTilesN) {
  __shared__ __align__(16) bf16_t As[2 * 256 * 64];
  __shared__ __align__(16) bf16_t Bs[2 * 256 * 64];
  const int tid = threadIdx.x;
  const int w = tid >> 6, lane = tid & 63;

  // T1: bijective XCD swizzle (gridDim.x % 8 == 0), ntile-fast decode.
  int nwg = gridDim.x;
  int chunk = nwg >> 3;
  int wgid = (blockIdx.x & 7) * chunk + (blockIdx.x >> 3);
  int mt = wgid / nTilesN, ntile = wgid % nTilesN;
  const int bm = mt * 256, bn = ntile * 256;

  const int wr = w >> 2, wc = w & 3;          // 2x4 wave grid; wave tile 128x64
  const int lr = lane & 15, lg = lane >> 4;
  const int sw = lr & 7;                      // T2 read-side XOR key
  const int nt = K >> 6;

  f32x4 acc[8][4] = {};

  auto stageHalf = [&](const bf16_t* __restrict__ G, int rbase, int kt, int ld,
                       bf16_t* lbuf, int h) {
#pragma unroll
    for (int j = 0; j < 2; ++j) {
      int b = j * 8 + w;
      int r3 = lane >> 3;
      int k8 = (lane & 7) ^ r3;               // T2 pre-swizzled source slot
      gl_lds16(G + (size_t)(rbase + h * 128 + b * 8 + r3) * ld + kt + k8 * 8,
               lbuf + h * 8192 + b * 512);
    }
  };

  // prologue: tiles 0 and 1 fully staged
  stageHalf(Bt, bn, 0, K, Bs, 0); stageHalf(Bt, bn, 0, K, Bs, 1);
  stageHalf(A, bm, 0, K, As, 0);  stageHalf(A, bm, 0, K, As, 1);
  if (nt > 1) {
    stageHalf(Bt, bn, 64, K, Bs + 16384, 0); stageHalf(Bt, bn, 64, K, Bs + 16384, 1);
    stageHalf(A, bm, 64, K, As + 16384, 0);  stageHalf(A, bm, 64, K, As + 16384, 1);
    asm volatile("s_waitcnt vmcnt(8)" ::: "memory");
  } else {
    asm volatile("s_waitcnt vmcnt(0)" ::: "memory");
  }
  __syncthreads();

  for (int t = 0; t < nt; ++t) {
    const int c = t & 1;
    bf16_t* Abuf = As + c * 16384;
    bf16_t* Bbuf = Bs + c * 16384;
    const bool pf = (t + 2) < nt;
    const int kt2 = (t + 2) << 6;
    bf16x8 bfrag[4][2];

#pragma unroll
    for (int p = 0; p < 4; ++p) {
      bf16x8 afrag[2][2];
#pragma unroll
      for (int fi = 0; fi < 2; ++fi)
#pragma unroll
        for (int kk = 0; kk < 2; ++kk)
          afrag[fi][kk] = *(const bf16x8*)&Abuf[(wr * 128 + p * 32 + fi * 16 + lr) * 64 +
                                                (((kk * 4 + lg) ^ sw) * 8)];
      if (p == 0) {
#pragma unroll
        for (int fj = 0; fj < 4; ++fj)
#pragma unroll
          for (int kk = 0; kk < 2; ++kk)
            bfrag[fj][kk] = *(const bf16x8*)&Bbuf[(wc * 64 + fj * 16 + lr) * 64 +
                                                  (((kk * 4 + lg) ^ sw) * 8)];
      }
      if (pf) {
        if (p == 1) stageHalf(Bt, bn, kt2, K, Bbuf, 0);
        if (p == 2) stageHalf(Bt, bn, kt2, K, Bbuf, 1);
        if (p == 3) { stageHalf(A, bm, kt2, K, Abuf, 0); stageHalf(A, bm, kt2, K, Abuf, 1); }
      }
      __builtin_amdgcn_s_barrier();
      asm volatile("s_waitcnt lgkmcnt(0)" ::: "memory");
      __builtin_amdgcn_sched_barrier(0);
      __builtin_amdgcn_s_setprio(1);
#pragma unroll
      for (int kk = 0; kk < 2; ++kk)
#pragma unroll
        for (int fi = 0; fi < 2; ++fi)
#pragma unroll
          for (int fj = 0; fj < 4; ++fj)
            acc[p * 2 + fi][fj] = __builtin_amdgcn_mfma_f32_16x16x32_bf16(
                afrag[fi][kk], bfrag[fj][kk], acc[p * 2 + fi][fj], 0, 0, 0);
      __builtin_amdgcn_s_setprio(0);
      if (p == 3) {
        if (pf) asm volatile("s_waitcnt vmcnt(8)" ::: "memory");   // t+1 fully landed
        else    asm volatile("s_waitcnt vmcnt(0)" ::: "memory");   // tail drain
      }
      __builtin_amdgcn_s_barrier();
    }
  }

#pragma unroll
  for (int fi = 0; fi < 8; ++fi)
#pragma unroll
    for (int fj = 0; fj < 4; ++fj)
#pragma unroll
      for (int r = 0; r < 4; ++r) {
        int row = bm + wr * 128 + fi * 16 + lg * 4 + r;
        int col = bn + wc * 64 + fj * 16 + lr;
        float v = acc[fi][fj][r];
        if (EPI == 0) {
          // scatter into pyramid level 0: col -> (tns, head, d)
          int tns = col >> 10, col10 = col & 1023;
          int h = col10 >> 6, d = col10 & 63;
          int hg = (row >> 13) * 16 + h;
          int trow = row & 8191;
          if (tns == 0) v *= 0.125f;          // q pre-scale (DIM_HEAD^-0.5)
          bf16_t* Pt = (tns == 0) ? Pq : (tns == 1 ? Pk : Pv);
          Pt[((size_t)hg * PROWS + trow) * 64 + d] = (bf16_t)v;
        } else {
          Cp[(size_t)row * ldc + col] = v + bias[col];
        }
      }
}

// ---------------------------------------------------------------- pyramid coarsen level l>=1 (d8 innermost: coalesced)
__global__ __launch_bounds__(256) void coarsen_lvl(bf16_t* __restrict__ Pq,
                                                   bf16_t* __restrict__ Pk,
                                                   bf16_t* __restrict__ Pv,
                                                   int mshift, int poffIn, int poffOut) {
  int gid = blockIdx.x * 256 + threadIdx.x;
  int d8 = gid & 7;
  int r = (gid >> 3) & ((1 << mshift) - 1);
  int hg = gid >> (3 + mshift);
  if (hg >= 64) return;
  size_t b0 = ((size_t)hg * PROWS + poffIn + 2 * r) * 64 + d8 * 8;
  size_t b1 = b0 + 64;
  size_t o = ((size_t)hg * PROWS + poffOut + r) * 64 + d8 * 8;
  float a0[8], a1[8], t[8];
  load8f(Pq + b0, a0); load8f(Pq + b1, a1);
#pragma unroll
  for (int e = 0; e < 8; ++e) t[e] = 0.5f * (a0[e] + a1[e]);
  store8f(Pq + o, t);
  load8f(Pk + b0, a0); load8f(Pk + b1, a1);
#pragma unroll
  for (int e = 0; e < 8; ++e) t[e] = 0.5f * (a0[e] + a1[e]);
  store8f(Pk + o, t);
  load8f(Pv + b0, a0); load8f(Pv + b1, a1);
#pragma unroll
  for (int e = 0; e < 8; ++e) t[e] = a0[e] + a1[e];
  store8f(Pv + o, t);
}

// ---------------------------------------------------------------- all-level 16x16 block attention, MFMA, 1 wave/block
// Levels 0..8; q pre-scaled in gemm1. 4 blocks per workgroup (1 per wave), no LDS.
// QK^T: S^T = mfma(K, Q) so lane(lg,lr) holds S[qr=lr][j=4lg+r] -> softmax is
// 3 VALU + 2 shfl_xor. P cast to bf16 (Asum from SAME bf16 values -> ratio
// error cancels). PV: mfma with K=16 zero-padded to 32; A-op needs
// A_exp[lr][8lg+e] -> 8 shfl from lanes 2lg/2lg+1; lanes lg>=2 hold zeros.
// Writes y (bf16) IN PLACE over the dead q rows of Pq.
__global__ __launch_bounds__(256) void attn_all(bf16_t* __restrict__ Pq,
                                                const bf16_t* __restrict__ Pk,
                                                const bf16_t* __restrict__ Pv,
                                                float* __restrict__ Asum) {
  const int poffA[9] = {0, 8192, 12288, 14336, 15360, 15872, 16128, 16256, 16320};
  const int tid = threadIdx.x;
  const int wv = tid >> 6, lane = tid & 63;
  const int lr = lane & 15, lg = lane >> 4;

  int bid = blockIdx.x * 4 + wv;            // 65408 block-attention problems
  int l = 0, cnt = 32768;
  while (bid >= cnt) { bid -= cnt; cnt >>= 1; ++l; }
  const int lg2nblk = 9 - l;
  const int blk = bid & ((1 << lg2nblk) - 1);
  const int hg = bid >> lg2nblk;
  const int kvblk = l ? (blk ^ 1) : blk;
  const size_t qbase = (size_t)hg * PROWS + poffA[l] + blk * 16;
  const size_t kvbase = (size_t)hg * PROWS + poffA[l] + kvblk * 16;

  // ---- QK^T: D = K x Q^T = S^T (K=64 in 2 chunks)
  f32x4 s = {};
#pragma unroll
  for (int c = 0; c < 2; ++c) {
    bf16x8 ak = *(const bf16x8*)(Pk + (kvbase + lr) * 64 + c * 32 + lg * 8);
    bf16x8 bq = *(const bf16x8*)(Pq + (qbase + lr) * 64 + c * 32 + lg * 8);
    s = __builtin_amdgcn_mfma_f32_16x16x32_bf16(ak, bq, s, 0, 0, 0);
  }

  // ---- softmax over j (in-lane r + lane-groups lg)
  float mx = fmaxf(fmaxf(s[0], s[1]), fmaxf(s[2], s[3]));
  mx = fmaxf(mx, __shfl_xor(mx, 16, 64));
  mx = fmaxf(mx, __shfl_xor(mx, 32, 64));
  float a[4];
  float asum = 0.f;
#pragma unroll
  for (int r = 0; r < 4; ++r) {
    a[r] = (float)(bf16_t)__expf(s[r] - mx);   // round through bf16 for consistency with PV
    asum += a[r];
  }
  asum += __shfl_xor(asum, 16, 64);
  asum += __shfl_xor(asum, 32, 64);
  if (lg == 0) Asum[qbase + lr] = asum;

  // ---- redistribute P to A-operand layout: A_exp[qr=lr][j=8lg+e]
  const int src0 = (2 * lg) * 16 + lr;
  const int src1 = (2 * lg + 1) * 16 + lr;
  bf16x8 pa;
#pragma unroll
  for (int r = 0; r < 4; ++r) {
    float c0 = __shfl(a[r], src0, 64);
    float c1 = __shfl(a[r], src1, 64);
    pa[r]     = (lg < 2) ? (bf16_t)c0 : (bf16_t)0.f;
    pa[r + 4] = (lg < 2) ? (bf16_t)c1 : (bf16_t)0.f;
  }

  // ---- PV: Y[16][64] in 4 d-tiles; K=16 zero-padded to 32 (lanes lg>=2 zero)
#pragma unroll
  for (int dt = 0; dt < 4; ++dt) {
    bf16x8 vf;
    if (lg < 2) {
#pragma unroll
      for (int e = 0; e < 8; ++e)
        vf[e] = Pv[(kvbase + lg * 8 + e) * 64 + dt * 16 + lr];
    } else {
#pragma unroll
      for (int e = 0; e < 8; ++e) vf[e] = (bf16_t)0.f;
    }
    f32x4 y = __builtin_amdgcn_mfma_f32_16x16x32_bf16(pa, vf, (f32x4){}, 0, 0, 0);
#pragma unroll
    for (int r = 0; r < 4; ++r)
      Pq[(qbase + 4 * lg + r) * 64 + dt * 16 + lr] = (bf16_t)y[r];
  }
}

// ---------------------------------------------------------------- combine levels + normalize -> attn bf16 [32768][1024]
__global__ __launch_bounds__(256) void combine_kernel(const bf16_t* __restrict__ Py,
                                                      const float* __restrict__ As,
                                                      bf16_t* __restrict__ attnb) {
  int gid = blockIdx.x * 256 + threadIdx.x;
  int d8 = gid & 7;
  int t = (gid >> 3) & 8191;
  int hg = gid >> 16;
  const int poffA[9] = {0, 8192, 12288, 14336, 15360, 15872, 16128, 16256, 16320};
  float acc[8] = {};
  float asum = 0.f;
#pragma unroll
  for (int l = 0; l < 9; ++l) {
    int rc = t >> l;
    size_t row = (size_t)hg * PROWS + poffA[l] + rc;
    asum += As[row];
    bf16x8 v = *(const bf16x8*)(Py + row * 64 + d8 * 8);
#pragma unroll
    for (int e = 0; e < 8; ++e) acc[e] += (float)v[e];
  }
  float inv = 1.f / (asum + 1e-8f);
  bf16x8 v;
#pragma unroll
  for (int e = 0; e < 8; ++e) v[e] = (bf16_t)(acc[e] * inv);
  *(bf16x8*)(attnb + ((size_t)(hg >> 4) * 8192 + t) * 1024 + (hg & 15) * 64 + d8 * 8) = v;
}

// ---------------------------------------------------------------- launch
// Workspace (bytes), total 481,550,336 (~459.2 MiB):
//   Pq @ 0           127.75 MiB  [64][16352][64] bf16 (q -> y in place)
//   Pk @ 133955584   127.75 MiB
//   Pv @ 267911168   127.75 MiB
//   Ab @ 401866752   4 MiB       [64][16352] f32 Asum
//   woutT @ 406052864  2 MiB
//   x_bf @ 408150016  64 MiB     (dead after gemm1)
//   wqkvT @ 475258880 6 MiB      (dead after gemm1)
// Alias: attnb @ 133955584 over Pk (Pk dead after attn_all; combine writes it).
extern "C" void kernel_launch(void* const* d_in, const int* in_sizes, int n_in,
                              void* d_out, int out_size, void* d_ws, size_t ws_size,
                              hipStream_t stream) {
  const float* x = (const float*)d_in[0];
  const float* wqkv = (const float*)d_in[1];
  const float* wout = (const float*)d_in[2];
  const float* bout = (const float*)d_in[3];
  float* out = (float*)d_out;
  (void)in_sizes; (void)n_in; (void)out_size; (void)ws_size;

  char* base = (char*)d_ws;
  bf16_t* Pq    = (bf16_t*)(base + 0);
  bf16_t* Pk    = (bf16_t*)(base + 133955584);
  bf16_t* Pv    = (bf16_t*)(base + 267911168);
  float*  Ab    = (float*)(base + 401866752);
  bf16_t* woutT = (bf16_t*)(base + 406052864);
  bf16_t* x_bf  = (bf16_t*)(base + 408150016);
  bf16_t* wqkvT = (bf16_t*)(base + 475258880);
  bf16_t* attnb = (bf16_t*)(base + 133955584);   // alias over Pk

  cvt_f32_to_bf16<<<16384, 256, 0, stream>>>(x, x_bf);
  transpose_to_bf16<<<dim3(96, 32), 256, 0, stream>>>(wqkv, wqkvT, 1024, 3072);
  transpose_to_bf16<<<dim3(32, 32), 256, 0, stream>>>(wout, woutT, 1024, 1024);

  // qkv GEMM -> scatter directly into pyramid level 0 (q scaled)
  gemm256<0><<<1536, 512, 0, stream>>>(x_bf, wqkvT, nullptr, nullptr, Pq, Pk, Pv,
                                       32768, 3072, 1024, 3072, 12);

  static const int poffA[9] = {0, 8192, 12288, 14336, 15360, 15872, 16128, 16256, 16320};
  for (int l = 1; l <= 8; ++l) {
    int mshift = 13 - l;
    coarsen_lvl<<<2 << mshift, 256, 0, stream>>>(Pq, Pk, Pv, mshift, poffA[l - 1], poffA[l]);
  }

  attn_all<<<16352, 256, 0, stream>>>(Pq, Pk, Pv, Ab);
  combine_kernel<<<16384, 256, 0, stream>>>(Pq, Ab, attnb);

  gemm256<1><<<512, 512, 0, stream>>>(attnb, woutT, out, bout, nullptr, nullptr, nullptr,
                                      32768, 1024, 1024, 1024, 4);
}

// Round 7
// 585.566 us; speedup vs baseline: 1.8730x; 1.1069x over previous
//
#include <hip/hip_runtime.h>
#include <hip/hip_bf16.h>

typedef __bf16 bf16_t;
typedef bf16_t bf16x8 __attribute__((ext_vector_type(8)));
typedef float f32x4 __attribute__((ext_vector_type(4)));

// Pyramid layout: P[hg][16352][64] bf16, hg = b*16+h (64 head-groups).
// Row offsets per level l (rows per hg = 8192>>l):
//   {0, 8192, 12288, 14336, 15360, 15872, 16128, 16256, 16320}, total 16352.
#define PROWS 16352

// ---------------------------------------------------------------- helpers
__device__ __forceinline__ void gl_lds16(const bf16_t* g, bf16_t* l) {
  __builtin_amdgcn_global_load_lds(
      (const __attribute__((address_space(1))) void*)g,
      (__attribute__((address_space(3))) void*)l,
      16, 0, 0);
}

__device__ __forceinline__ void load8f(const bf16_t* p, float* f) {
  bf16x8 v = *(const bf16x8*)p;
#pragma unroll
  for (int e = 0; e < 8; ++e) f[e] = (float)v[e];
}
__device__ __forceinline__ void store8f(bf16_t* p, const float* f) {
  bf16x8 v;
#pragma unroll
  for (int e = 0; e < 8; ++e) v[e] = (bf16_t)f[e];
  *(bf16x8*)p = v;
}

// ---------------------------------------------------------------- fp32 -> bf16 (x)
__global__ __launch_bounds__(256) void cvt_f32_to_bf16(const float* __restrict__ in,
                                                       bf16_t* __restrict__ o) {
  size_t gid = (size_t)blockIdx.x * 256 + threadIdx.x;
  const float4* p = (const float4*)in + gid * 2;
  float4 a = p[0], b = p[1];
  bf16x8 v;
  v[0] = (bf16_t)a.x; v[1] = (bf16_t)a.y; v[2] = (bf16_t)a.z; v[3] = (bf16_t)a.w;
  v[4] = (bf16_t)b.x; v[5] = (bf16_t)b.y; v[6] = (bf16_t)b.z; v[7] = (bf16_t)b.w;
  *(bf16x8*)(o + gid * 8) = v;
}

// ---------------------------------------------------------------- weight transpose + cast: w[K][N] -> wT[N][K] bf16
__global__ __launch_bounds__(256) void transpose_to_bf16(const float* __restrict__ w,
                                                         bf16_t* __restrict__ wT,
                                                         int K, int N) {
  __shared__ float t[32][33];
  int bx = blockIdx.x, by = blockIdx.y;
  int tx = threadIdx.x & 31, ty = threadIdx.x >> 5;
#pragma unroll
  for (int r = ty; r < 32; r += 8)
    t[r][tx] = w[(size_t)(by * 32 + r) * N + bx * 32 + tx];
  __syncthreads();
#pragma unroll
  for (int r = ty; r < 32; r += 8)
    wT[(size_t)(bx * 32 + r) * K + by * 32 + tx] = (bf16_t)t[tx][r];
}

// ---------------------------------------------------------------- persistent 256x256 8-phase GEMM (T1+T2+T3+T4+T5)
// C[M][N] = A[M][K=1024] @ Bt[N][K=1024]^T.  8 waves, BK=64, dbuf LDS 128 KiB.
// PERSISTENT: grid = 256 blocks exactly; each block runs tilesPerBlock output
// tiles as ONE flattened pipeline (16 K-steps per tile). Stage of step g+2
// crosses tile boundaries; epilogue of tile T overlaps staged loads of T+1;
// fill/drain paid once per block instead of per round.
// T2 swizzle: k-slot' = k-slot ^ (row&7); linear gload_lds dest + pre-swizzled
// global source + swizzled ds_read (rule #21).
// EPI 0: scatter bf16 into pyramid P (qkv de-interleave, q scaled 0.125).
// EPI 1: fp32 C + bias.
template <int EPI>
__global__ __launch_bounds__(512, 2) void gemm256p(const bf16_t* __restrict__ A,
                                                   const bf16_t* __restrict__ Bt,
                                                   float* __restrict__ Cp,
                                                   const float* __restrict__ bias,
                                                   bf16_t* __restrict__ Pq,
                                                   bf16_t* __restrict__ Pk,
                                                   bf16_t* __restrict__ Pv,
                                                   int ldc, int nTilesN, int tilesPerBlock) {
  __shared__ __align__(16) bf16_t As[2 * 256 * 64];
  __shared__ __align__(16) bf16_t Bs[2 * 256 * 64];
  const int LD = 1024;                        // K for both GEMMs
  const int tid = threadIdx.x;
  const int w = tid >> 6, lane = tid & 63;

  // chunk map: XCD x gets chunks {x*32 .. x*32+31}; adjacent chunks share A-panel.
  const int chunk = (blockIdx.x & 7) * 32 + (blockIdx.x >> 3);
  const int tile0 = chunk * tilesPerBlock;
  const int nSteps = tilesPerBlock * 16;

  const int wr = w >> 2, wc = w & 3;          // 2x4 wave grid; wave tile 128x64
  const int lr = lane & 15, lg = lane >> 4;
  const int sw = lr & 7;                      // T2 read-side XOR key
  f32x4 acc[8][4] = {};

  auto stageHalf = [&](const bf16_t* __restrict__ G, int rbase, int kt,
                       bf16_t* lbuf, int h) {
#pragma unroll
    for (int j = 0; j < 2; ++j) {
      int b = j * 8 + w;
      int r3 = lane >> 3;
      int k8 = (lane & 7) ^ r3;               // T2 pre-swizzled source slot
      gl_lds16(G + (size_t)(rbase + h * 128 + b * 8 + r3) * LD + kt + k8 * 8,
               lbuf + h * 8192 + b * 512);
    }
  };

  // prologue: steps 0 and 1 (both inside tile0)
  {
    int mt = tile0 / nTilesN, nt0 = tile0 % nTilesN;
    int bm = mt * 256, bn = nt0 * 256;
    stageHalf(Bt, bn, 0, Bs, 0); stageHalf(Bt, bn, 0, Bs, 1);
    stageHalf(A, bm, 0, As, 0);  stageHalf(A, bm, 0, As, 1);
    stageHalf(Bt, bn, 64, Bs + 16384, 0); stageHalf(Bt, bn, 64, Bs + 16384, 1);
    stageHalf(A, bm, 64, As + 16384, 0);  stageHalf(A, bm, 64, As + 16384, 1);
    asm volatile("s_waitcnt vmcnt(8)" ::: "memory");   // step 0 landed
  }
  __syncthreads();

  for (int g = 0; g < nSteps; ++g) {
    const int tile = tile0 + (g >> 4);
    const int ktl = g & 15;
    const int c = g & 1;
    bf16_t* Abuf = As + c * 16384;
    bf16_t* Bbuf = Bs + c * 16384;
    const int g2 = g + 2;
    const bool pf = g2 < nSteps;
    const int t2 = tile0 + (g2 >> 4);
    const int mt2 = t2 / nTilesN, nt2v = t2 % nTilesN;
    const int bm2 = mt2 * 256, bn2 = nt2v * 256;
    const int kt2 = (g2 & 15) << 6;
    bf16x8 bfrag[4][2];

#pragma unroll
    for (int p = 0; p < 4; ++p) {
      bf16x8 afrag[2][2];
#pragma unroll
      for (int fi = 0; fi < 2; ++fi)
#pragma unroll
        for (int kk = 0; kk < 2; ++kk)
          afrag[fi][kk] = *(const bf16x8*)&Abuf[(wr * 128 + p * 32 + fi * 16 + lr) * 64 +
                                                (((kk * 4 + lg) ^ sw) * 8)];
      if (p == 0) {
#pragma unroll
        for (int fj = 0; fj < 4; ++fj)
#pragma unroll
          for (int kk = 0; kk < 2; ++kk)
            bfrag[fj][kk] = *(const bf16x8*)&Bbuf[(wc * 64 + fj * 16 + lr) * 64 +
                                                  (((kk * 4 + lg) ^ sw) * 8)];
      }
      if (pf) {
        if (p == 1) stageHalf(Bt, bn2, kt2, Bbuf, 0);
        if (p == 2) stageHalf(Bt, bn2, kt2, Bbuf, 1);
        if (p == 3) { stageHalf(A, bm2, kt2, Abuf, 0); stageHalf(A, bm2, kt2, Abuf, 1); }
      }
      __builtin_amdgcn_s_barrier();
      asm volatile("s_waitcnt lgkmcnt(0)" ::: "memory");
      __builtin_amdgcn_sched_barrier(0);
      __builtin_amdgcn_s_setprio(1);
#pragma unroll
      for (int kk = 0; kk < 2; ++kk)
#pragma unroll
        for (int fi = 0; fi < 2; ++fi)
#pragma unroll
          for (int fj = 0; fj < 4; ++fj)
            acc[p * 2 + fi][fj] = __builtin_amdgcn_mfma_f32_16x16x32_bf16(
                afrag[fi][kk], bfrag[fj][kk], acc[p * 2 + fi][fj], 0, 0, 0);
      __builtin_amdgcn_s_setprio(0);
      if (p == 3) {
        if (pf) asm volatile("s_waitcnt vmcnt(8)" ::: "memory");   // step g+1 landed
        else    asm volatile("s_waitcnt vmcnt(0)" ::: "memory");   // tail drain
      }
      __builtin_amdgcn_s_barrier();
    }

    if (ktl == 15) {
      // ---- epilogue for this tile (overlaps next tile's staged loads)
      const int mt = tile / nTilesN, ntv = tile % nTilesN;
      const int bm = mt * 256, bn = ntv * 256;
      if (EPI == 1) {
        float bv[4];
#pragma unroll
        for (int fj = 0; fj < 4; ++fj) bv[fj] = bias[bn + wc * 64 + fj * 16 + lr];
#pragma unroll
        for (int fi = 0; fi < 8; ++fi)
#pragma unroll
          for (int fj = 0; fj < 4; ++fj)
#pragma unroll
            for (int r = 0; r < 4; ++r) {
              int row = bm + wr * 128 + fi * 16 + lg * 4 + r;
              int col = bn + wc * 64 + fj * 16 + lr;
              Cp[(size_t)row * ldc + col] = acc[fi][fj][r] + bv[fj];
            }
      } else {
#pragma unroll
        for (int fi = 0; fi < 8; ++fi)
#pragma unroll
          for (int fj = 0; fj < 4; ++fj)
#pragma unroll
            for (int r = 0; r < 4; ++r) {
              int row = bm + wr * 128 + fi * 16 + lg * 4 + r;
              int col = bn + wc * 64 + fj * 16 + lr;
              float v = acc[fi][fj][r];
              int tns = col >> 10, col10 = col & 1023;
              int h = col10 >> 6, d = col10 & 63;
              int hg = (row >> 13) * 16 + h;
              int trow = row & 8191;
              if (tns == 0) v *= 0.125f;      // q pre-scale (DIM_HEAD^-0.5)
              bf16_t* Pt = (tns == 0) ? Pq : (tns == 1 ? Pk : Pv);
              Pt[((size_t)hg * PROWS + trow) * 64 + d] = (bf16_t)v;
            }
      }
#pragma unroll
      for (int fi = 0; fi < 8; ++fi)
#pragma unroll
        for (int fj = 0; fj < 4; ++fj) acc[fi][fj] = (f32x4){};
    }
  }
}

// ---------------------------------------------------------------- fused pyramid coarsen, levels 1..8, one dispatch
// Block = (hg, window of 512 level-0 rows); 512 thr; levels 1-3 in registers,
// 4-6 via shfl_xor(8/16/32), 7-8 via small LDS hop. q,k: mean; v: sum.
// All chains kept in f32; each level's global write is a single bf16 round.
__global__ __launch_bounds__(512) void coarsen_tree(bf16_t* __restrict__ Pq,
                                                    bf16_t* __restrict__ Pk,
                                                    bf16_t* __restrict__ Pv) {
  __shared__ float l6s[8][64];
  const int poffA[9] = {0, 8192, 12288, 14336, 15360, 15872, 16128, 16256, 16320};
  const int hg = blockIdx.x >> 4, win = blockIdx.x & 15;
  const int tid = threadIdx.x;
  const int d8 = tid & 7;            // 16B d-segment
  const int tb = tid >> 3;           // row-block 0..63
  const int wv = tid >> 6;           // wave 0..7
  const size_t base = (size_t)hg * PROWS;
  const int r0 = win * 512 + tb * 8;

#pragma unroll 1
  for (int tensor = 0; tensor < 3; ++tensor) {
    bf16_t* P = (tensor == 0) ? Pq : (tensor == 1 ? Pk : Pv);
    const float sc = (tensor == 2) ? 1.f : 0.5f;
    float v[8][8];
#pragma unroll
    for (int i = 0; i < 8; ++i) load8f(P + (base + r0 + i) * 64 + d8 * 8, v[i]);
    // level 1 (4 rows/thread)
    float a1[4][8];
#pragma unroll
    for (int i = 0; i < 4; ++i) {
#pragma unroll
      for (int e = 0; e < 8; ++e) a1[i][e] = sc * (v[2 * i][e] + v[2 * i + 1][e]);
      store8f(P + (base + poffA[1] + win * 256 + tb * 4 + i) * 64 + d8 * 8, a1[i]);
    }
    // level 2 (2 rows/thread)
    float a2[2][8];
#pragma unroll
    for (int i = 0; i < 2; ++i) {
#pragma unroll
      for (int e = 0; e < 8; ++e) a2[i][e] = sc * (a1[2 * i][e] + a1[2 * i + 1][e]);
      store8f(P + (base + poffA[2] + win * 128 + tb * 2 + i) * 64 + d8 * 8, a2[i]);
    }
    // level 3 (1 row/thread)
    float a3[8];
#pragma unroll
    for (int e = 0; e < 8; ++e) a3[e] = sc * (a2[0][e] + a2[1][e]);
    store8f(P + (base + poffA[3] + win * 64 + tb) * 64 + d8 * 8, a3);
    // level 4: partner tb^1 (tid^8)
    float a4[8];
#pragma unroll
    for (int e = 0; e < 8; ++e) a4[e] = sc * (a3[e] + __shfl_xor(a3[e], 8, 64));
    if ((tb & 1) == 0) store8f(P + (base + poffA[4] + win * 32 + (tb >> 1)) * 64 + d8 * 8, a4);
    // level 5: partner tb^2 (tid^16)
    float a5[8];
#pragma unroll
    for (int e = 0; e < 8; ++e) a5[e] = sc * (a4[e] + __shfl_xor(a4[e], 16, 64));
    if ((tb & 3) == 0) store8f(P + (base + poffA[5] + win * 16 + (tb >> 2)) * 64 + d8 * 8, a5);
    // level 6: partner tb^4 (tid^32)
    float a6[8];
#pragma unroll
    for (int e = 0; e < 8; ++e) a6[e] = sc * (a5[e] + __shfl_xor(a5[e], 32, 64));
    if ((tb & 7) == 0) {
      bf16x8 o;
#pragma unroll
      for (int e = 0; e < 8; ++e) { l6s[wv][d8 * 8 + e] = a6[e]; o[e] = (bf16_t)a6[e]; }
      *(bf16x8*)(P + (base + poffA[6] + win * 8 + wv) * 64 + d8 * 8) = o;
    }
    __syncthreads();
    // levels 7 (4 rows) and 8 (2 rows) from l6s
    if (tid < 32) {
      int pr = tid >> 3;             // 0..3
      float a7[8];
#pragma unroll
      for (int e = 0; e < 8; ++e)
        a7[e] = sc * (l6s[2 * pr][d8 * 8 + e] + l6s[2 * pr + 1][d8 * 8 + e]);
      store8f(P + (base + poffA[7] + win * 4 + pr) * 64 + d8 * 8, a7);
      if (pr < 2) {
        float a8[8];
#pragma unroll
        for (int e = 0; e < 8; ++e)
          a8[e] = sc * (sc * (l6s[4 * pr][d8 * 8 + e] + l6s[4 * pr + 1][d8 * 8 + e]) +
                        sc * (l6s[4 * pr + 2][d8 * 8 + e] + l6s[4 * pr + 3][d8 * 8 + e]));
        store8f(P + (base + poffA[8] + win * 2 + pr) * 64 + d8 * 8, a8);
      }
    }
    __syncthreads();                 // protect l6s before next tensor
  }
}

// ---------------------------------------------------------------- all-level 16x16 block attention, MFMA, 1 wave/block
__global__ __launch_bounds__(256) void attn_all(bf16_t* __restrict__ Pq,
                                                const bf16_t* __restrict__ Pk,
                                                const bf16_t* __restrict__ Pv,
                                                float* __restrict__ Asum) {
  const int poffA[9] = {0, 8192, 12288, 14336, 15360, 15872, 16128, 16256, 16320};
  const int tid = threadIdx.x;
  const int wv = tid >> 6, lane = tid & 63;
  const int lr = lane & 15, lg = lane >> 4;

  int bid = blockIdx.x * 4 + wv;            // 65408 block-attention problems
  int l = 0, cnt = 32768;
  while (bid >= cnt) { bid -= cnt; cnt >>= 1; ++l; }
  const int lg2nblk = 9 - l;
  const int blk = bid & ((1 << lg2nblk) - 1);
  const int hg = bid >> lg2nblk;
  const int kvblk = l ? (blk ^ 1) : blk;
  const size_t qbase = (size_t)hg * PROWS + poffA[l] + blk * 16;
  const size_t kvbase = (size_t)hg * PROWS + poffA[l] + kvblk * 16;

  // ---- QK^T: D = K x Q^T = S^T (K=64 in 2 chunks)
  f32x4 s = {};
#pragma unroll
  for (int c = 0; c < 2; ++c) {
    bf16x8 ak = *(const bf16x8*)(Pk + (kvbase + lr) * 64 + c * 32 + lg * 8);
    bf16x8 bq = *(const bf16x8*)(Pq + (qbase + lr) * 64 + c * 32 + lg * 8);
    s = __builtin_amdgcn_mfma_f32_16x16x32_bf16(ak, bq, s, 0, 0, 0);
  }

  // ---- softmax over j (in-lane r + lane-groups lg)
  float mx = fmaxf(fmaxf(s[0], s[1]), fmaxf(s[2], s[3]));
  mx = fmaxf(mx, __shfl_xor(mx, 16, 64));
  mx = fmaxf(mx, __shfl_xor(mx, 32, 64));
  float a[4];
  float asum = 0.f;
#pragma unroll
  for (int r = 0; r < 4; ++r) {
    a[r] = (float)(bf16_t)__expf(s[r] - mx);   // round through bf16 for consistency with PV
    asum += a[r];
  }
  asum += __shfl_xor(asum, 16, 64);
  asum += __shfl_xor(asum, 32, 64);
  if (lg == 0) Asum[qbase + lr] = asum;

  // ---- redistribute P to A-operand layout: A_exp[qr=lr][j=8lg+e]
  const int src0 = (2 * lg) * 16 + lr;
  const int src1 = (2 * lg + 1) * 16 + lr;
  bf16x8 pa;
#pragma unroll
  for (int r = 0; r < 4; ++r) {
    float c0 = __shfl(a[r], src0, 64);
    float c1 = __shfl(a[r], src1, 64);
    pa[r]     = (lg < 2) ? (bf16_t)c0 : (bf16_t)0.f;
    pa[r + 4] = (lg < 2) ? (bf16_t)c1 : (bf16_t)0.f;
  }

  // ---- PV: Y[16][64] in 4 d-tiles; K=16 zero-padded to 32 (lanes lg>=2 zero)
#pragma unroll
  for (int dt = 0; dt < 4; ++dt) {
    bf16x8 vf;
    if (lg < 2) {
#pragma unroll
      for (int e = 0; e < 8; ++e)
        vf[e] = Pv[(kvbase + lg * 8 + e) * 64 + dt * 16 + lr];
    } else {
#pragma unroll
      for (int e = 0; e < 8; ++e) vf[e] = (bf16_t)0.f;
    }
    f32x4 y = __builtin_amdgcn_mfma_f32_16x16x32_bf16(pa, vf, (f32x4){}, 0, 0, 0);
#pragma unroll
    for (int r = 0; r < 4; ++r)
      Pq[(qbase + 4 * lg + r) * 64 + dt * 16 + lr] = (bf16_t)y[r];
  }
}

// ---------------------------------------------------------------- combine levels + normalize -> attn bf16 [32768][1024]
__global__ __launch_bounds__(256) void combine_kernel(const bf16_t* __restrict__ Py,
                                                      const float* __restrict__ As,
                                                      bf16_t* __restrict__ attnb) {
  int gid = blockIdx.x * 256 + threadIdx.x;
  int d8 = gid & 7;
  int t = (gid >> 3) & 8191;
  int hg = gid >> 16;
  const int poffA[9] = {0, 8192, 12288, 14336, 15360, 15872, 16128, 16256, 16320};
  float acc[8] = {};
  float asum = 0.f;
#pragma unroll
  for (int l = 0; l < 9; ++l) {
    int rc = t >> l;
    size_t row = (size_t)hg * PROWS + poffA[l] + rc;
    asum += As[row];
    bf16x8 v = *(const bf16x8*)(Py + row * 64 + d8 * 8);
#pragma unroll
    for (int e = 0; e < 8; ++e) acc[e] += (float)v[e];
  }
  float inv = 1.f / (asum + 1e-8f);
  bf16x8 v;
#pragma unroll
  for (int e = 0; e < 8; ++e) v[e] = (bf16_t)(acc[e] * inv);
  *(bf16x8*)(attnb + ((size_t)(hg >> 4) * 8192 + t) * 1024 + (hg & 15) * 64 + d8 * 8) = v;
}

// ---------------------------------------------------------------- launch
// Workspace (bytes), total 481,550,336 (~459.2 MiB):
//   Pq @ 0           127.75 MiB  [64][16352][64] bf16 (q -> y in place)
//   Pk @ 133955584   127.75 MiB
//   Pv @ 267911168   127.75 MiB
//   Ab @ 401866752   4 MiB       [64][16352] f32 Asum
//   woutT @ 406052864  2 MiB
//   x_bf @ 408150016  64 MiB     (dead after gemm1)
//   wqkvT @ 475258880 6 MiB      (dead after gemm1)
// Alias: attnb @ 133955584 over Pk (Pk dead after attn_all; combine writes it).
extern "C" void kernel_launch(void* const* d_in, const int* in_sizes, int n_in,
                              void* d_out, int out_size, void* d_ws, size_t ws_size,
                              hipStream_t stream) {
  const float* x = (const float*)d_in[0];
  const float* wqkv = (const float*)d_in[1];
  const float* wout = (const float*)d_in[2];
  const float* bout = (const float*)d_in[3];
  float* out = (float*)d_out;
  (void)in_sizes; (void)n_in; (void)out_size; (void)ws_size;

  char* base = (char*)d_ws;
  bf16_t* Pq    = (bf16_t*)(base + 0);
  bf16_t* Pk    = (bf16_t*)(base + 133955584);
  bf16_t* Pv    = (bf16_t*)(base + 267911168);
  float*  Ab    = (float*)(base + 401866752);
  bf16_t* woutT = (bf16_t*)(base + 406052864);
  bf16_t* x_bf  = (bf16_t*)(base + 408150016);
  bf16_t* wqkvT = (bf16_t*)(base + 475258880);
  bf16_t* attnb = (bf16_t*)(base + 133955584);   // alias over Pk

  cvt_f32_to_bf16<<<16384, 256, 0, stream>>>(x, x_bf);
  transpose_to_bf16<<<dim3(96, 32), 256, 0, stream>>>(wqkv, wqkvT, 1024, 3072);
  transpose_to_bf16<<<dim3(32, 32), 256, 0, stream>>>(wout, woutT, 1024, 1024);

  // qkv GEMM (persistent, 6 tiles/block) -> scatter into pyramid level 0
  gemm256p<0><<<256, 512, 0, stream>>>(x_bf, wqkvT, nullptr, nullptr, Pq, Pk, Pv,
                                       3072, 12, 6);

  coarsen_tree<<<1024, 512, 0, stream>>>(Pq, Pk, Pv);

  attn_all<<<16352, 256, 0, stream>>>(Pq, Pk, Pv, Ab);
  combine_kernel<<<16384, 256, 0, stream>>>(Pq, Ab, attnb);

  // output GEMM (persistent, 2 tiles/block), fp32 + bias
  gemm256p<1><<<256, 512, 0, stream>>>(attnb, woutT, out, bout, nullptr, nullptr, nullptr,
                                       1024, 4, 2);
}